// Round 7
// baseline (462.084 us; speedup 1.0000x reference)
//
#include <hip/hip_runtime.h>
#include <cstddef>
#include <cstdint>

#define Bc 4
#define Nc 1024
#define Cc 768
#define Hc 12
#define Dc 64
#define BHc 48
#define QKV_ELEMS ((size_t)Bc * Nc * Cc)   // 3145728

typedef __attribute__((ext_vector_type(4))) unsigned int u32x4;
typedef __attribute__((ext_vector_type(2))) unsigned int u32x2;
typedef __attribute__((ext_vector_type(8))) short s16x8;
typedef __attribute__((ext_vector_type(8))) _Float16 h16x8;
typedef __attribute__((ext_vector_type(4))) float fx4;
typedef __attribute__((ext_vector_type(2))) float fx2;

union Frag { u32x4 u; s16x8 s; h16x8 f16; unsigned short h[8]; };

__device__ inline unsigned short f2bf(float x) {
    union { float f; uint32_t u; } c; c.f = x;
    return (unsigned short)((c.u + 0x7FFFu + ((c.u >> 16) & 1u)) >> 16);
}
__device__ inline float bf2f(unsigned short b) {
    union { uint32_t u; float f; } c; c.u = ((uint32_t)b) << 16;
    return c.f;
}
__device__ inline void split8(const float* v, u32x4& hi, u32x4& lo) {
    Frag fh, fl;
    #pragma unroll
    for (int e = 0; e < 8; ++e) {
        const unsigned short hb = f2bf(v[e]);
        fh.h[e] = hb;
        fl.h[e] = f2bf(v[e] - bf2f(hb));
    }
    hi = fh.u; lo = fl.u;
}
__device__ inline void split8h(const float* v, u32x4& hi, u32x4& lo) {
    Frag fh, fl;
    #pragma unroll
    for (int e = 0; e < 8; ++e) {
        const _Float16 hb = (_Float16)v[e];
        fh.f16[e] = hb;
        fl.f16[e] = (_Float16)(v[e] - (float)hb);
    }
    hi = fh.u; lo = fl.u;
}

// ---------------------------------------------------------------------------
// prep_w: Wt_hi/lo[mat][n][k] = split(W[k][n])  (bf16 hi/lo)
// ---------------------------------------------------------------------------
__global__ __launch_bounds__(256) void prep_w_kernel(
    const float* __restrict__ Wq, const float* __restrict__ Wk,
    const float* __restrict__ Wv, const float* __restrict__ Wo,
    unsigned short* __restrict__ Thi, unsigned short* __restrict__ Tlo)
{
    __shared__ float scr[64 * 65];
    const int mat = blockIdx.z;
    const float* W = (mat == 0) ? Wq : (mat == 1) ? Wk : (mat == 2) ? Wv : Wo;
    const int k0 = blockIdx.y * 64, n0 = blockIdx.x * 64;
    const int tid = threadIdx.x;

    #pragma unroll
    for (int it = 0; it < 4; ++it) {
        const int lin = tid + it * 256;
        const int r = lin >> 4, c4 = (lin & 15) << 2;
        const fx4 v = *(const fx4*)&W[(size_t)(k0 + r) * 768 + n0 + c4];
        scr[r * 65 + c4 + 0] = v[0]; scr[r * 65 + c4 + 1] = v[1];
        scr[r * 65 + c4 + 2] = v[2]; scr[r * 65 + c4 + 3] = v[3];
    }
    __syncthreads();
    unsigned short* th = Thi + (size_t)mat * 768 * 768;
    unsigned short* tl = Tlo + (size_t)mat * 768 * 768;
    #pragma unroll
    for (int it = 0; it < 16; ++it) {
        const int lin = tid + it * 256;
        const int n = lin >> 6, kq = lin & 63;
        const float val = scr[kq * 65 + n];
        const size_t o = (size_t)(n0 + n) * 768 + k0 + kq;
        const unsigned short hb = f2bf(val);
        th[o] = hb;
        tl[o] = f2bf(val - bf2f(hb));
    }
}

// ---------------------------------------------------------------------------
// prep_tables: PL (alpha,beta) per (segment, h) + 2048-bin u8 idx LUT.
// ---------------------------------------------------------------------------
__global__ __launch_bounds__(256) void prep_tables_kernel(
    const float* __restrict__ Wd1, const float* __restrict__ bd1,
    const float* __restrict__ Wd2, const float* __restrict__ bd2,
    float* __restrict__ abPack, unsigned char* __restrict__ lut)
{
    __shared__ float w1s[16], b1s[16], kn[16];
    __shared__ int rank[16];
    const int tid = threadIdx.x;
    if (tid < 16) {
        const float w1 = Wd1[tid], b1 = bd1[tid];
        w1s[tid] = w1; b1s[tid] = b1;
        kn[tid] = (w1 != 0.0f) ? (-b1 / w1) : INFINITY;
    }
    __syncthreads();
    if (tid < 16) {
        int rk = 0;
        for (int u = 0; u < 16; ++u) {
            const float ku = kn[u], km = kn[tid];
            if (ku < km || (ku == km && u < tid)) ++rk;
        }
        rank[tid] = rk;
    }
    __syncthreads();
    if (tid < 17 * 12) {
        const int s = tid / 12, h = tid % 12;
        float a = 0.0f, be = bd2[h];
        for (int u = 0; u < 16; ++u) {
            const float w1 = w1s[u], b1 = b1s[u];
            bool act;
            if (w1 > 0.0f)      act = (rank[u] < s);
            else if (w1 < 0.0f) act = (rank[u] >= s);
            else                act = (b1 > 0.0f);
            if (act) {
                const float w2 = Wd2[u * 12 + h];
                a  += w2 * w1;
                be += w2 * b1;
            }
        }
        abPack[tid * 2 + 0] = a;
        abPack[tid * 2 + 1] = be;
    }
    for (int b = tid; b < 2048; b += 256) {
        const float rep = (b + 0.5f) * (1.41422f / 2048.0f);
        int cnt = 0;
        for (int t = 0; t < 16; ++t) cnt += (rep > kn[t]) ? 1 : 0;
        lut[b] = (unsigned char)cnt;
    }
}

// ---------------------------------------------------------------------------
// split_x: x fp32 -> xhi/xlo bf16 row-major
// ---------------------------------------------------------------------------
__global__ __launch_bounds__(256) void split_x_kernel(
    const float* __restrict__ x, unsigned short* __restrict__ xhi,
    unsigned short* __restrict__ xlo)
{
    const size_t t = (size_t)blockIdx.x * 256 + threadIdx.x;
    float vv[8];
    const fx4 a = *(const fx4*)&x[t * 8];
    const fx4 b = *(const fx4*)&x[t * 8 + 4];
    vv[0]=a[0]; vv[1]=a[1]; vv[2]=a[2]; vv[3]=a[3];
    vv[4]=b[0]; vv[5]=b[1]; vv[6]=b[2]; vv[7]=b[3];
    u32x4 hi, lo; split8(vv, hi, lo);
    *(u32x4*)&xhi[t * 8] = hi;
    *(u32x4*)&xlo[t * 8] = lo;
}

// ---------------------------------------------------------------------------
// gemm_mfma: out = A[4096x768] @ W[768x768] + bias, bf16x3 MFMA.
// OMODE 0: bf16 hi/lo head layout [bh][n][d] (q,k)
// OMODE 1: f16 hi/lo vT [bh][d][n] (v)
// OMODE 2: fp32 row-major (final out)
// ---------------------------------------------------------------------------
struct SmemG { u32x4 ah[512]; u32x4 al[512]; u32x4 bh[512]; u32x4 bl[512]; };
struct SmemT { float scr[64 * 68]; };
union SmemU { SmemG g; SmemT t; };

template<int OMODE>
__global__ __launch_bounds__(256) void gemm_mfma_kernel(
    const unsigned short* __restrict__ Ahi, const unsigned short* __restrict__ Alo,
    const unsigned short* __restrict__ Bhi, const unsigned short* __restrict__ Blo,
    const float* __restrict__ bias,
    float* __restrict__ outF,
    unsigned short* __restrict__ Ohi, unsigned short* __restrict__ Olo)
{
    __shared__ SmemU sm;
    const int tid = threadIdx.x;
    const int w = tid >> 6, L = tid & 63;
    const int Lr = L & 15, Lg = L >> 4;
    const int m0 = blockIdx.y * 64, n0 = blockIdx.x * 64;

    fx4 acc[2][2] = {};

    for (int kk = 0; kk < 768; kk += 64) {
        #pragma unroll
        for (int it = 0; it < 2; ++it) {
            const int slot = tid + it * 256;
            const int s = slot >> 6, l = slot & 63;
            const int row = m0 + ((s >> 1) << 4) + (l & 15);
            const int kb = kk + ((s & 1) << 5) + ((l >> 4) << 3);
            sm.g.ah[slot] = *(const u32x4*)&Ahi[(size_t)row * 768 + kb];
            sm.g.al[slot] = *(const u32x4*)&Alo[(size_t)row * 768 + kb];
            const int col = n0 + ((s >> 1) << 4) + (l & 15);
            sm.g.bh[slot] = *(const u32x4*)&Bhi[(size_t)col * 768 + kb];
            sm.g.bl[slot] = *(const u32x4*)&Blo[(size_t)col * 768 + kb];
        }
        __syncthreads();
        #pragma unroll
        for (int kc = 0; kc < 2; ++kc) {
            Frag ah[2], al[2], bh[2], bl[2];
            #pragma unroll
            for (int mm = 0; mm < 2; ++mm) {
                const int rg = (w >> 1) * 2 + mm;
                ah[mm].u = sm.g.ah[(rg * 2 + kc) * 64 + L];
                al[mm].u = sm.g.al[(rg * 2 + kc) * 64 + L];
            }
            #pragma unroll
            for (int nn = 0; nn < 2; ++nn) {
                const int cg = (w & 1) * 2 + nn;
                bh[nn].u = sm.g.bh[(cg * 2 + kc) * 64 + L];
                bl[nn].u = sm.g.bl[(cg * 2 + kc) * 64 + L];
            }
            #pragma unroll
            for (int mm = 0; mm < 2; ++mm)
                #pragma unroll
                for (int nn = 0; nn < 2; ++nn) {
                    acc[mm][nn] = __builtin_amdgcn_mfma_f32_16x16x32_bf16(ah[mm].s, bh[nn].s, acc[mm][nn], 0, 0, 0);
                    acc[mm][nn] = __builtin_amdgcn_mfma_f32_16x16x32_bf16(ah[mm].s, bl[nn].s, acc[mm][nn], 0, 0, 0);
                    acc[mm][nn] = __builtin_amdgcn_mfma_f32_16x16x32_bf16(al[mm].s, bh[nn].s, acc[mm][nn], 0, 0, 0);
                }
        }
        __syncthreads();
    }

    #pragma unroll
    for (int mm = 0; mm < 2; ++mm) {
        const int rl = (w >> 1) * 32 + mm * 16 + Lg * 4;
        #pragma unroll
        for (int nn = 0; nn < 2; ++nn) {
            const int cl = (w & 1) * 32 + nn * 16 + Lr;
            const float bs = bias[n0 + cl];
            #pragma unroll
            for (int r = 0; r < 4; ++r)
                sm.t.scr[(rl + r) * 68 + cl] = acc[mm][nn][r] + bs;
        }
    }
    __syncthreads();

    if (OMODE == 0) {
        const int h = n0 >> 6;
        #pragma unroll
        for (int it = 0; it < 2; ++it) {
            const int t = tid + it * 256;
            const int r = t >> 3, d0 = (t & 7) << 3;
            float vv[8];
            #pragma unroll
            for (int e = 0; e < 8; ++e) vv[e] = sm.t.scr[r * 68 + d0 + e];
            u32x4 hi, lo; split8(vv, hi, lo);
            const int rg = m0 + r, b = rg >> 10, nloc = rg & 1023;
            const size_t o = (((size_t)(b * Hc + h) * Nc + nloc) << 6) + d0;
            *(u32x4*)&Ohi[o] = hi;
            *(u32x4*)&Olo[o] = lo;
        }
    } else if (OMODE == 1) {
        const int b = m0 >> 10, h = n0 >> 6, nbase = m0 & 1023;
        #pragma unroll
        for (int it = 0; it < 2; ++it) {
            const int t = tid + it * 256;
            const int dd = t >> 3, j0 = (t & 7) << 3;
            float vv[8];
            #pragma unroll
            for (int e = 0; e < 8; ++e) vv[e] = sm.t.scr[(j0 + e) * 68 + dd];
            u32x4 hi, lo; split8h(vv, hi, lo);   // f16 hi/lo for PV
            const size_t o = (size_t)((b * Hc + h) * Dc + dd) * Nc + nbase + j0;
            *(u32x4*)&Ohi[o] = hi;
            *(u32x4*)&Olo[o] = lo;
        }
    } else {
        #pragma unroll
        for (int it = 0; it < 4; ++it) {
            const int lin = tid + it * 256;
            const int r = lin >> 4, c4 = (lin & 15) << 2;
            const fx4 v = *(const fx4*)&sm.t.scr[r * 68 + c4];
            *(fx4*)&outF[(size_t)(m0 + r) * 768 + n0 + c4] = v;
        }
    }
}

// ---------------------------------------------------------------------------
// attn_fused: pass1 QK^T+spatial -> e (f16, REGISTERS) + m_t[16] + online m,l;
// pass2 V (LDS frag-order) + per-wave LDS e-permute -> attn (write once) + PV.
// Block: 64 rows x bh; 4 waves x 16 rows. No global intermediate.
// ---------------------------------------------------------------------------
union PvSmem {
    struct { u32x4 vh[512]; u32x4 vl[512]; } v;
    float scr[64 * 68];
};

__global__ __launch_bounds__(256) void attn_fused_kernel(
    const unsigned short* __restrict__ qhi, const unsigned short* __restrict__ qlo,
    const unsigned short* __restrict__ khi, const unsigned short* __restrict__ klo,
    const unsigned short* __restrict__ vThi, const unsigned short* __restrict__ vTlo,
    const float* __restrict__ coords,
    const float* __restrict__ abPack, const unsigned char* __restrict__ lutg,
    float* __restrict__ attn,
    unsigned short* __restrict__ Hphi, unsigned short* __restrict__ Hplo)
{
    __shared__ PvSmem sm;
    __shared__ char escr[4 * 2048];          // per-wave e permute scratch
    __shared__ fx2 cjs[1024];
    __shared__ unsigned char luts[2048];
    __shared__ fx2 abt[17];

    const int tid = threadIdx.x;
    const int w = tid >> 6, L = tid & 63;
    const int Lr = L & 15, Lg = L >> 4;
    const int bh = blockIdx.y, b = bh / Hc, h = bh % Hc;
    const int i0 = blockIdx.x * 64;
    const int i = i0 + w * 16 + Lr;
    const int Lg4 = Lg * 4;

    if (tid < 17) abt[tid] = ((const fx2*)abPack)[tid * Hc + h];
    #pragma unroll
    for (int t = tid; t < 512; t += 256)
        ((uint32_t*)luts)[t] = ((const uint32_t*)lutg)[t];
    #pragma unroll
    for (int t = tid; t < 1024; t += 256)
        cjs[t] = *(const fx2*)&coords[((size_t)b * Nc + t) * 2];

    Frag qh[2], ql[2];
    #pragma unroll
    for (int kc = 0; kc < 2; ++kc) {
        const size_t o = ((size_t)bh * Nc + i) * 64 + kc * 32 + Lg * 8;
        qh[kc].u = *(const u32x4*)&qhi[o];
        ql[kc].u = *(const u32x4*)&qlo[o];
    }
    const fx2 ci = *(const fx2*)&coords[((size_t)b * Nc + i) * 2];
    __syncthreads();

    // ---------------- pass 1: scores -> e in registers ----------------
    Frag ef[16][2];
    float m_t[16];
    float m_r = -INFINITY, l_r = 0.f;

    #pragma unroll
    for (int jt = 0; jt < 16; ++jt) {
        const int jbase = jt * 64;

        fx4 acc[4] = {};
        #pragma unroll
        for (int kc = 0; kc < 2; ++kc) {
            Frag kh[4], kl[4];
            #pragma unroll
            for (int cg = 0; cg < 4; ++cg) {
                const size_t o = ((size_t)bh * Nc + jbase + cg * 16 + Lr) * 64 + kc * 32 + Lg * 8;
                kh[cg].u = *(const u32x4*)&khi[o];
                kl[cg].u = *(const u32x4*)&klo[o];
            }
            #pragma unroll
            for (int cg = 0; cg < 4; ++cg) {
                acc[cg] = __builtin_amdgcn_mfma_f32_16x16x32_bf16(kh[cg].s, qh[kc].s, acc[cg], 0, 0, 0);
                acc[cg] = __builtin_amdgcn_mfma_f32_16x16x32_bf16(kl[cg].s, qh[kc].s, acc[cg], 0, 0, 0);
                acc[cg] = __builtin_amdgcn_mfma_f32_16x16x32_bf16(kh[cg].s, ql[kc].s, acc[cg], 0, 0, 0);
            }
        }

        float sv[16];
        #pragma unroll
        for (int cg = 0; cg < 4; ++cg) {
            #pragma unroll
            for (int r = 0; r < 4; ++r) {
                const fx2 cj = cjs[jbase + cg * 16 + Lg4 + r];
                const float dx = ci[0] - cj[0], dy = ci[1] - cj[1];
                const float dist = sqrtf(fmaf(dx, dx, fmaf(dy, dy, 1e-6f)));
                int bin = (int)(dist * (2048.0f / 1.41422f));
                bin = (bin > 2047) ? 2047 : bin;
                const fx2 ab = abt[luts[bin]];
                sv[cg * 4 + r] = fmaf(acc[cg][r], 0.125f, fmaf(ab[0], dist, ab[1]));
            }
        }

        float tm = sv[0];
        #pragma unroll
        for (int e = 1; e < 16; ++e) tm = fmaxf(tm, sv[e]);
        tm = fmaxf(tm, __shfl_xor(tm, 16));
        tm = fmaxf(tm, __shfl_xor(tm, 32));
        m_t[jt] = tm;

        float ts = 0.f;
        #pragma unroll
        for (int e = 0; e < 16; ++e) { sv[e] = __expf(sv[e] - tm); ts += sv[e]; }
        ts += __shfl_xor(ts, 16);
        ts += __shfl_xor(ts, 32);

        // pack e as f16: ef[jt][p].h[0..3] = cg=2p, h[4..7] = cg=2p+1
        #pragma unroll
        for (int p = 0; p < 2; ++p) {
            Frag f;
            #pragma unroll
            for (int r = 0; r < 4; ++r) {
                f.f16[r]     = (_Float16)sv[(2 * p) * 4 + r];
                f.f16[4 + r] = (_Float16)sv[(2 * p + 1) * 4 + r];
            }
            ef[jt][p] = f;
        }

        const float mnew = fmaxf(m_r, tm);
        l_r = l_r * __expf(m_r - mnew) + ts * __expf(tm - mnew);
        m_r = mnew;
    }

    const float m_row = m_r;
    const float il = 1.0f / l_r;

    // ---------------- pass 2: attn write + PV ----------------
    char* ebase = escr + w * 2048;
    fx4 oacc[4] = {};
    const size_t arow = ((size_t)bh * Nc + i) * Nc;

    #pragma unroll
    for (int jt = 0; jt < 16; ++jt) {
        const int jbase = jt * 64;
        // stage V tile (frag-order)
        #pragma unroll
        for (int it = 0; it < 2; ++it) {
            const int s = tid + it * 256;
            const int l = s & 63;
            const int dd = ((s >> 7) << 4) + (l & 15);
            const int jo = jbase + ((s >> 6) & 1) * 32 + ((l >> 4) << 3);
            const size_t off = ((size_t)bh * Dc + dd) * Nc + jo;
            sm.v.vh[s] = *(const u32x4*)&vThi[off];
            sm.v.vl[s] = *(const u32x4*)&vTlo[off];
        }

        // e permute: score-layout regs -> per-wave LDS -> A-frag layout
        #pragma unroll
        for (int p = 0; p < 2; ++p) {
            const Frag f = ef[jt][p];
            u32x2 lo2, hi2;
            lo2[0] = f.u[0]; lo2[1] = f.u[1];
            hi2[0] = f.u[2]; hi2[1] = f.u[3];
            const int j0 = (2 * p) * 16 + Lg4;
            const int j1 = (2 * p + 1) * 16 + Lg4;
            *(u32x2*)(ebase + ((Lr * 128 + j0 * 2) ^ ((Lr & 7) << 4))) = lo2;
            *(u32x2*)(ebase + ((Lr * 128 + j1 * 2) ^ ((Lr & 7) << 4))) = hi2;
        }
        __syncthreads();   // V staged + e scratch written

        const float fscale = __expf(m_t[jt] - m_row) * il;
        const _Float16 fh = (_Float16)fscale;

        #pragma unroll
        for (int kc = 0; kc < 2; ++kc) {
            Frag eA;
            eA.u = *(u32x4*)(ebase + ((Lr * 128 + (kc * 32 + Lg * 8) * 2) ^ ((Lr & 7) << 4)));
            // attn write-once (f32)
            float pf[8];
            #pragma unroll
            for (int e = 0; e < 8; ++e) pf[e] = (float)eA.f16[e] * fscale;
            fx4 w0, w1;
            w0[0]=pf[0]; w0[1]=pf[1]; w0[2]=pf[2]; w0[3]=pf[3];
            w1[0]=pf[4]; w1[1]=pf[5]; w1[2]=pf[6]; w1[3]=pf[7];
            float* ap = &attn[arow + jbase + kc * 32 + Lg * 8];
            *(fx4*)ap = w0;
            *(fx4*)(ap + 4) = w1;
            // PV
            Frag pa;
            pa.f16 = eA.f16 * fh;
            #pragma unroll
            for (int dg = 0; dg < 4; ++dg) {
                Frag vh, vl;
                vh.u = sm.v.vh[(dg * 2 + kc) * 64 + L];
                vl.u = sm.v.vl[(dg * 2 + kc) * 64 + L];
                oacc[dg] = __builtin_amdgcn_mfma_f32_16x16x32_f16(pa.f16, vh.f16, oacc[dg], 0, 0, 0);
                oacc[dg] = __builtin_amdgcn_mfma_f32_16x16x32_f16(pa.f16, vl.f16, oacc[dg], 0, 0, 0);
            }
        }
        __syncthreads();   // before next jt overwrites V/e scratch
    }

    // epilogue: heads via LDS + vectorized bf16 hi/lo store
    #pragma unroll
    for (int dg = 0; dg < 4; ++dg)
        #pragma unroll
        for (int r = 0; r < 4; ++r)
            sm.scr[(w * 16 + Lg * 4 + r) * 68 + dg * 16 + Lr] = oacc[dg][r];
    __syncthreads();

    #pragma unroll
    for (int it = 0; it < 2; ++it) {
        const int lin = tid + it * 256;
        const int row = lin >> 3, d0 = (lin & 7) << 3;
        float vv[8];
        #pragma unroll
        for (int e = 0; e < 8; ++e) vv[e] = sm.scr[row * 68 + d0 + e];
        u32x4 hi, lo; split8(vv, hi, lo);
        const size_t o = ((size_t)b * Nc + i0 + row) * Cc + h * Dc + d0;
        *(u32x4*)&Hphi[o] = hi;
        *(u32x4*)&Hplo[o] = lo;
    }
}

// ---------------------------------------------------------------------------
extern "C" void kernel_launch(void* const* d_in, const int* in_sizes, int n_in,
                              void* d_out, int out_size, void* d_ws, size_t ws_size,
                              hipStream_t stream)
{
    (void)in_sizes; (void)n_in; (void)out_size; (void)ws_size;

    const float* x      = (const float*)d_in[0];
    const float* coords = (const float*)d_in[1];
    const float* Wq = (const float*)d_in[2];  const float* bq = (const float*)d_in[3];
    const float* Wk = (const float*)d_in[4];  const float* bk = (const float*)d_in[5];
    const float* Wv = (const float*)d_in[6];  const float* bv = (const float*)d_in[7];
    const float* Wo = (const float*)d_in[8];  const float* bo = (const float*)d_in[9];
    const float* Wd1 = (const float*)d_in[10]; const float* bd1 = (const float*)d_in[11];
    const float* Wd2 = (const float*)d_in[12]; const float* bd2 = (const float*)d_in[13];

    float* out_main = (float*)d_out;            // [B,N,C]
    float* attn     = out_main + QKV_ELEMS;     // [B,H,N,N]

    uint8_t* wsb = (uint8_t*)d_ws;
    const size_t SZ_BF = (size_t)BHc * Nc * Dc * 2;          // 6,291,456 B
    const size_t SZ_W4 = (size_t)4 * 768 * 768 * 2;          // 4,718,592 B
    unsigned short* qhi  = (unsigned short*)(wsb + 0 * SZ_BF);
    unsigned short* qlo  = (unsigned short*)(wsb + 1 * SZ_BF);
    unsigned short* khi  = (unsigned short*)(wsb + 2 * SZ_BF);
    unsigned short* klo  = (unsigned short*)(wsb + 3 * SZ_BF);
    unsigned short* vThi = (unsigned short*)(wsb + 4 * SZ_BF);
    unsigned short* vTlo = (unsigned short*)(wsb + 5 * SZ_BF);
    unsigned short* xhi  = (unsigned short*)(wsb + 6 * SZ_BF); // reused as Hphi
    unsigned short* xlo  = (unsigned short*)(wsb + 7 * SZ_BF); // reused as Hplo
    unsigned short* Thi  = (unsigned short*)(wsb + 8 * SZ_BF);
    unsigned short* Tlo  = (unsigned short*)(wsb + 8 * SZ_BF + SZ_W4);
    float* abPack = (float*)(wsb + 8 * SZ_BF + 2 * SZ_W4);   // 17*12*2 floats
    unsigned char* lut = (unsigned char*)(abPack + 17 * 12 * 2); // 2048 B

    prep_w_kernel<<<dim3(12, 12, 4), 256, 0, stream>>>(Wq, Wk, Wv, Wo, Thi, Tlo);
    prep_tables_kernel<<<1, 256, 0, stream>>>(Wd1, bd1, Wd2, bd2, abPack, lut);
    split_x_kernel<<<dim3(1536), 256, 0, stream>>>(x, xhi, xlo);

    dim3 gGemm(12, 64);
    gemm_mfma_kernel<0><<<gGemm, 256, 0, stream>>>(
        xhi, xlo, Thi + (size_t)0 * 768 * 768, Tlo + (size_t)0 * 768 * 768,
        bq, nullptr, qhi, qlo);
    gemm_mfma_kernel<0><<<gGemm, 256, 0, stream>>>(
        xhi, xlo, Thi + (size_t)1 * 768 * 768, Tlo + (size_t)1 * 768 * 768,
        bk, nullptr, khi, klo);
    gemm_mfma_kernel<1><<<gGemm, 256, 0, stream>>>(
        xhi, xlo, Thi + (size_t)2 * 768 * 768, Tlo + (size_t)2 * 768 * 768,
        bv, nullptr, vThi, vTlo);

    attn_fused_kernel<<<dim3(16, 48), 256, 0, stream>>>(
        qhi, qlo, khi, klo, vThi, vTlo, coords, abPack, lut,
        attn, xhi, xlo);

    gemm_mfma_kernel<2><<<gGemm, 256, 0, stream>>>(
        xhi, xlo, Thi + (size_t)3 * 768 * 768, Tlo + (size_t)3 * 768 * 768,
        bo, out_main, nullptr, nullptr);
}

// Round 9
// 424.760 us; speedup vs baseline: 1.0879x; 1.0879x over previous
//
#include <hip/hip_runtime.h>
#include <cstddef>
#include <cstdint>

#define Bc 4
#define Nc 1024
#define Cc 768
#define Hc 12
#define Dc 64
#define BHc 48
#define QKV_ELEMS ((size_t)Bc * Nc * Cc)   // 3145728

typedef __attribute__((ext_vector_type(4))) unsigned int u32x4;
typedef __attribute__((ext_vector_type(2))) unsigned int u32x2;
typedef __attribute__((ext_vector_type(8))) short s16x8;
typedef __attribute__((ext_vector_type(8))) _Float16 h16x8;
typedef __attribute__((ext_vector_type(4))) float fx4;
typedef __attribute__((ext_vector_type(2))) float fx2;

union Frag { u32x4 u; s16x8 s; h16x8 f16; unsigned short h[8]; };
union H4 { u32x2 d; _Float16 h[4]; };

__device__ inline unsigned short f2bf(float x) {
    union { float f; uint32_t u; } c; c.f = x;
    return (unsigned short)((c.u + 0x7FFFu + ((c.u >> 16) & 1u)) >> 16);
}
__device__ inline float bf2f(unsigned short b) {
    union { uint32_t u; float f; } c; c.u = ((uint32_t)b) << 16;
    return c.f;
}
__device__ inline void split8(const float* v, u32x4& hi, u32x4& lo) {
    Frag fh, fl;
    #pragma unroll
    for (int e = 0; e < 8; ++e) {
        const unsigned short hb = f2bf(v[e]);
        fh.h[e] = hb;
        fl.h[e] = f2bf(v[e] - bf2f(hb));
    }
    hi = fh.u; lo = fl.u;
}
__device__ inline void split8h(const float* v, u32x4& hi, u32x4& lo) {
    Frag fh, fl;
    #pragma unroll
    for (int e = 0; e < 8; ++e) {
        const _Float16 hb = (_Float16)v[e];
        fh.f16[e] = hb;
        fl.f16[e] = (_Float16)(v[e] - (float)hb);
    }
    hi = fh.u; lo = fl.u;
}

// ---------------------------------------------------------------------------
// prep_w: Wt_hi/lo[mat][n][k] = split(W[k][n])  (bf16 hi/lo)
// ---------------------------------------------------------------------------
__global__ __launch_bounds__(256) void prep_w_kernel(
    const float* __restrict__ Wq, const float* __restrict__ Wk,
    const float* __restrict__ Wv, const float* __restrict__ Wo,
    unsigned short* __restrict__ Thi, unsigned short* __restrict__ Tlo)
{
    __shared__ float scr[64 * 65];
    const int mat = blockIdx.z;
    const float* W = (mat == 0) ? Wq : (mat == 1) ? Wk : (mat == 2) ? Wv : Wo;
    const int k0 = blockIdx.y * 64, n0 = blockIdx.x * 64;
    const int tid = threadIdx.x;

    #pragma unroll
    for (int it = 0; it < 4; ++it) {
        const int lin = tid + it * 256;
        const int r = lin >> 4, c4 = (lin & 15) << 2;
        const fx4 v = *(const fx4*)&W[(size_t)(k0 + r) * 768 + n0 + c4];
        scr[r * 65 + c4 + 0] = v[0]; scr[r * 65 + c4 + 1] = v[1];
        scr[r * 65 + c4 + 2] = v[2]; scr[r * 65 + c4 + 3] = v[3];
    }
    __syncthreads();
    unsigned short* th = Thi + (size_t)mat * 768 * 768;
    unsigned short* tl = Tlo + (size_t)mat * 768 * 768;
    #pragma unroll
    for (int it = 0; it < 16; ++it) {
        const int lin = tid + it * 256;
        const int n = lin >> 6, kq = lin & 63;
        const float val = scr[kq * 65 + n];
        const size_t o = (size_t)(n0 + n) * 768 + k0 + kq;
        const unsigned short hb = f2bf(val);
        th[o] = hb;
        tl[o] = f2bf(val - bf2f(hb));
    }
}

// ---------------------------------------------------------------------------
// prep_tables: PL (alpha,beta) per (segment, h) + 2048-bin u8 idx LUT.
// ---------------------------------------------------------------------------
__global__ __launch_bounds__(256) void prep_tables_kernel(
    const float* __restrict__ Wd1, const float* __restrict__ bd1,
    const float* __restrict__ Wd2, const float* __restrict__ bd2,
    float* __restrict__ abPack, unsigned char* __restrict__ lut)
{
    __shared__ float w1s[16], b1s[16], kn[16];
    __shared__ int rank[16];
    const int tid = threadIdx.x;
    if (tid < 16) {
        const float w1 = Wd1[tid], b1 = bd1[tid];
        w1s[tid] = w1; b1s[tid] = b1;
        kn[tid] = (w1 != 0.0f) ? (-b1 / w1) : INFINITY;
    }
    __syncthreads();
    if (tid < 16) {
        int rk = 0;
        for (int u = 0; u < 16; ++u) {
            const float ku = kn[u], km = kn[tid];
            if (ku < km || (ku == km && u < tid)) ++rk;
        }
        rank[tid] = rk;
    }
    __syncthreads();
    if (tid < 17 * 12) {
        const int s = tid / 12, h = tid % 12;
        float a = 0.0f, be = bd2[h];
        for (int u = 0; u < 16; ++u) {
            const float w1 = w1s[u], b1 = b1s[u];
            bool act;
            if (w1 > 0.0f)      act = (rank[u] < s);
            else if (w1 < 0.0f) act = (rank[u] >= s);
            else                act = (b1 > 0.0f);
            if (act) {
                const float w2 = Wd2[u * 12 + h];
                a  += w2 * w1;
                be += w2 * b1;
            }
        }
        abPack[tid * 2 + 0] = a;
        abPack[tid * 2 + 1] = be;
    }
    for (int b = tid; b < 2048; b += 256) {
        const float rep = (b + 0.5f) * (1.41422f / 2048.0f);
        int cnt = 0;
        for (int t = 0; t < 16; ++t) cnt += (rep > kn[t]) ? 1 : 0;
        lut[b] = (unsigned char)cnt;
    }
}

// ---------------------------------------------------------------------------
// split_x: x fp32 -> xhi/xlo bf16 row-major
// ---------------------------------------------------------------------------
__global__ __launch_bounds__(256) void split_x_kernel(
    const float* __restrict__ x, unsigned short* __restrict__ xhi,
    unsigned short* __restrict__ xlo)
{
    const size_t t = (size_t)blockIdx.x * 256 + threadIdx.x;
    float vv[8];
    const fx4 a = *(const fx4*)&x[t * 8];
    const fx4 b = *(const fx4*)&x[t * 8 + 4];
    vv[0]=a[0]; vv[1]=a[1]; vv[2]=a[2]; vv[3]=a[3];
    vv[4]=b[0]; vv[5]=b[1]; vv[6]=b[2]; vv[7]=b[3];
    u32x4 hi, lo; split8(vv, hi, lo);
    *(u32x4*)&xhi[t * 8] = hi;
    *(u32x4*)&xlo[t * 8] = lo;
}

// ---------------------------------------------------------------------------
// shared GEMM smem
// ---------------------------------------------------------------------------
struct SmemG { u32x4 ah[512]; u32x4 al[512]; u32x4 bh[512]; u32x4 bl[512]; };
struct SmemT { float scr[64 * 68]; };
union SmemU { SmemG g; SmemT t; };

// ---------------------------------------------------------------------------
// qkv_kernel: fused Q/K/V projections. grid (12 n-tiles, 64 m-tiles, 3 mats).
// mat 0/1 -> bf16 hi/lo head layout (q,k); mat 2 -> f16 hi/lo vT.
// ---------------------------------------------------------------------------
__global__ __launch_bounds__(256) void qkv_kernel(
    const unsigned short* __restrict__ xhi, const unsigned short* __restrict__ xlo,
    const unsigned short* __restrict__ Thi, const unsigned short* __restrict__ Tlo,
    const float* __restrict__ bq, const float* __restrict__ bk,
    const float* __restrict__ bv,
    unsigned short* __restrict__ qhi, unsigned short* __restrict__ qlo,
    unsigned short* __restrict__ khi, unsigned short* __restrict__ klo,
    unsigned short* __restrict__ vThi, unsigned short* __restrict__ vTlo)
{
    __shared__ SmemU sm;
    const int tid = threadIdx.x;
    const int w = tid >> 6, L = tid & 63;
    const int Lr = L & 15, Lg = L >> 4;
    const int m0 = blockIdx.y * 64, n0 = blockIdx.x * 64;
    const int mat = blockIdx.z;

    const unsigned short* Bhi = Thi + (size_t)mat * 768 * 768;
    const unsigned short* Blo = Tlo + (size_t)mat * 768 * 768;
    const float* bias = (mat == 0) ? bq : (mat == 1) ? bk : bv;

    fx4 acc[2][2] = {};

    for (int kk = 0; kk < 768; kk += 64) {
        #pragma unroll
        for (int it = 0; it < 2; ++it) {
            const int slot = tid + it * 256;
            const int s = slot >> 6, l = slot & 63;
            const int row = m0 + ((s >> 1) << 4) + (l & 15);
            const int kb = kk + ((s & 1) << 5) + ((l >> 4) << 3);
            sm.g.ah[slot] = *(const u32x4*)&xhi[(size_t)row * 768 + kb];
            sm.g.al[slot] = *(const u32x4*)&xlo[(size_t)row * 768 + kb];
            const int col = n0 + ((s >> 1) << 4) + (l & 15);
            sm.g.bh[slot] = *(const u32x4*)&Bhi[(size_t)col * 768 + kb];
            sm.g.bl[slot] = *(const u32x4*)&Blo[(size_t)col * 768 + kb];
        }
        __syncthreads();
        #pragma unroll
        for (int kc = 0; kc < 2; ++kc) {
            Frag ah[2], al[2], bh[2], bl[2];
            #pragma unroll
            for (int mm = 0; mm < 2; ++mm) {
                const int rg = (w >> 1) * 2 + mm;
                ah[mm].u = sm.g.ah[(rg * 2 + kc) * 64 + L];
                al[mm].u = sm.g.al[(rg * 2 + kc) * 64 + L];
            }
            #pragma unroll
            for (int nn = 0; nn < 2; ++nn) {
                const int cg = (w & 1) * 2 + nn;
                bh[nn].u = sm.g.bh[(cg * 2 + kc) * 64 + L];
                bl[nn].u = sm.g.bl[(cg * 2 + kc) * 64 + L];
            }
            #pragma unroll
            for (int mm = 0; mm < 2; ++mm)
                #pragma unroll
                for (int nn = 0; nn < 2; ++nn) {
                    acc[mm][nn] = __builtin_amdgcn_mfma_f32_16x16x32_bf16(ah[mm].s, bh[nn].s, acc[mm][nn], 0, 0, 0);
                    acc[mm][nn] = __builtin_amdgcn_mfma_f32_16x16x32_bf16(ah[mm].s, bl[nn].s, acc[mm][nn], 0, 0, 0);
                    acc[mm][nn] = __builtin_amdgcn_mfma_f32_16x16x32_bf16(al[mm].s, bh[nn].s, acc[mm][nn], 0, 0, 0);
                }
        }
        __syncthreads();
    }

    #pragma unroll
    for (int mm = 0; mm < 2; ++mm) {
        const int rl = (w >> 1) * 32 + mm * 16 + Lg * 4;
        #pragma unroll
        for (int nn = 0; nn < 2; ++nn) {
            const int cl = (w & 1) * 32 + nn * 16 + Lr;
            const float bs = bias[n0 + cl];
            #pragma unroll
            for (int r = 0; r < 4; ++r)
                sm.t.scr[(rl + r) * 68 + cl] = acc[mm][nn][r] + bs;
        }
    }
    __syncthreads();

    if (mat < 2) {
        unsigned short* Ohi = (mat == 0) ? qhi : khi;
        unsigned short* Olo = (mat == 0) ? qlo : klo;
        const int h = n0 >> 6;
        #pragma unroll
        for (int it = 0; it < 2; ++it) {
            const int t = tid + it * 256;
            const int r = t >> 3, d0 = (t & 7) << 3;
            float vv[8];
            #pragma unroll
            for (int e = 0; e < 8; ++e) vv[e] = sm.t.scr[r * 68 + d0 + e];
            u32x4 hi, lo; split8(vv, hi, lo);
            const int rg = m0 + r, b = rg >> 10, nloc = rg & 1023;
            const size_t o = (((size_t)(b * Hc + h) * Nc + nloc) << 6) + d0;
            *(u32x4*)&Ohi[o] = hi;
            *(u32x4*)&Olo[o] = lo;
        }
    } else {
        const int b = m0 >> 10, h = n0 >> 6, nbase = m0 & 1023;
        #pragma unroll
        for (int it = 0; it < 2; ++it) {
            const int t = tid + it * 256;
            const int dd = t >> 3, j0 = (t & 7) << 3;
            float vv[8];
            #pragma unroll
            for (int e = 0; e < 8; ++e) vv[e] = sm.t.scr[(j0 + e) * 68 + dd];
            u32x4 hi, lo; split8h(vv, hi, lo);   // f16 hi/lo for PV
            const size_t o = (size_t)((b * Hc + h) * Dc + dd) * Nc + nbase + j0;
            *(u32x4*)&vThi[o] = hi;
            *(u32x4*)&vTlo[o] = lo;
        }
    }
}

// ---------------------------------------------------------------------------
// gemm_mfma<2>: out-projection (fp32 row-major).
// ---------------------------------------------------------------------------
template<int OMODE>
__global__ __launch_bounds__(256) void gemm_mfma_kernel(
    const unsigned short* __restrict__ Ahi, const unsigned short* __restrict__ Alo,
    const unsigned short* __restrict__ Bhi, const unsigned short* __restrict__ Blo,
    const float* __restrict__ bias,
    float* __restrict__ outF)
{
    __shared__ SmemU sm;
    const int tid = threadIdx.x;
    const int w = tid >> 6, L = tid & 63;
    const int Lr = L & 15, Lg = L >> 4;
    const int m0 = blockIdx.y * 64, n0 = blockIdx.x * 64;

    fx4 acc[2][2] = {};

    for (int kk = 0; kk < 768; kk += 64) {
        #pragma unroll
        for (int it = 0; it < 2; ++it) {
            const int slot = tid + it * 256;
            const int s = slot >> 6, l = slot & 63;
            const int row = m0 + ((s >> 1) << 4) + (l & 15);
            const int kb = kk + ((s & 1) << 5) + ((l >> 4) << 3);
            sm.g.ah[slot] = *(const u32x4*)&Ahi[(size_t)row * 768 + kb];
            sm.g.al[slot] = *(const u32x4*)&Alo[(size_t)row * 768 + kb];
            const int col = n0 + ((s >> 1) << 4) + (l & 15);
            sm.g.bh[slot] = *(const u32x4*)&Bhi[(size_t)col * 768 + kb];
            sm.g.bl[slot] = *(const u32x4*)&Blo[(size_t)col * 768 + kb];
        }
        __syncthreads();
        #pragma unroll
        for (int kc = 0; kc < 2; ++kc) {
            Frag ah[2], al[2], bh[2], bl[2];
            #pragma unroll
            for (int mm = 0; mm < 2; ++mm) {
                const int rg = (w >> 1) * 2 + mm;
                ah[mm].u = sm.g.ah[(rg * 2 + kc) * 64 + L];
                al[mm].u = sm.g.al[(rg * 2 + kc) * 64 + L];
            }
            #pragma unroll
            for (int nn = 0; nn < 2; ++nn) {
                const int cg = (w & 1) * 2 + nn;
                bh[nn].u = sm.g.bh[(cg * 2 + kc) * 64 + L];
                bl[nn].u = sm.g.bl[(cg * 2 + kc) * 64 + L];
            }
            #pragma unroll
            for (int mm = 0; mm < 2; ++mm)
                #pragma unroll
                for (int nn = 0; nn < 2; ++nn) {
                    acc[mm][nn] = __builtin_amdgcn_mfma_f32_16x16x32_bf16(ah[mm].s, bh[nn].s, acc[mm][nn], 0, 0, 0);
                    acc[mm][nn] = __builtin_amdgcn_mfma_f32_16x16x32_bf16(ah[mm].s, bl[nn].s, acc[mm][nn], 0, 0, 0);
                    acc[mm][nn] = __builtin_amdgcn_mfma_f32_16x16x32_bf16(al[mm].s, bh[nn].s, acc[mm][nn], 0, 0, 0);
                }
        }
        __syncthreads();
    }

    #pragma unroll
    for (int mm = 0; mm < 2; ++mm) {
        const int rl = (w >> 1) * 32 + mm * 16 + Lg * 4;
        #pragma unroll
        for (int nn = 0; nn < 2; ++nn) {
            const int cl = (w & 1) * 32 + nn * 16 + Lr;
            const float bs = bias[n0 + cl];
            #pragma unroll
            for (int r = 0; r < 4; ++r)
                sm.t.scr[(rl + r) * 68 + cl] = acc[mm][nn][r] + bs;
        }
    }
    __syncthreads();

    #pragma unroll
    for (int it = 0; it < 4; ++it) {
        const int lin = tid + it * 256;
        const int r = lin >> 4, c4 = (lin & 15) << 2;
        const fx4 v = *(const fx4*)&sm.t.scr[r * 68 + c4];
        *(fx4*)&outF[(size_t)(m0 + r) * 768 + n0 + c4] = v;
    }
}

// ---------------------------------------------------------------------------
// attn_flash: single pass over jt with online rescaling.
// FIX vs r8: accumulator rows are Lg*4+r (not Lr) -> rescale factors and il
// must be fetched via __shfl from lane (Lg*4+r).
// ---------------------------------------------------------------------------
union FlashSmem {
    struct { u32x4 vh[512]; u32x4 vl[512]; char escr[4 * 2304]; } p;  // 25600 B
    float scr[64 * 68];                                               // 17408 B
};

__global__ __launch_bounds__(256) void attn_flash_kernel(
    const unsigned short* __restrict__ qhi, const unsigned short* __restrict__ qlo,
    const unsigned short* __restrict__ khi, const unsigned short* __restrict__ klo,
    const unsigned short* __restrict__ vThi, const unsigned short* __restrict__ vTlo,
    const float* __restrict__ coords,
    const float* __restrict__ abPack, const unsigned char* __restrict__ lutg,
    unsigned short* __restrict__ e_ws, float* __restrict__ mT,
    float* __restrict__ mlfin,
    unsigned short* __restrict__ Hphi, unsigned short* __restrict__ Hplo)
{
    __shared__ FlashSmem sm;
    __shared__ fx2 cjs[1024];
    __shared__ unsigned char luts[2048];
    __shared__ fx2 abt[17];

    const int tid = threadIdx.x;
    const int w = tid >> 6, L = tid & 63;
    const int Lr = L & 15, Lg = L >> 4;
    const int bh = blockIdx.y, b = bh / Hc, h = bh % Hc;
    const int i0 = blockIdx.x * 64;
    const int i = i0 + w * 16 + Lr;
    const int Lg4 = Lg * 4;

    if (tid < 17) abt[tid] = ((const fx2*)abPack)[tid * Hc + h];
    for (int t = tid; t < 512; t += 256)
        ((uint32_t*)luts)[t] = ((const uint32_t*)lutg)[t];
    for (int t = tid; t < 1024; t += 256)
        cjs[t] = *(const fx2*)&coords[((size_t)b * Nc + t) * 2];

    Frag qh[2], ql[2];
    #pragma unroll
    for (int kc = 0; kc < 2; ++kc) {
        const size_t o = ((size_t)bh * Nc + i) * 64 + kc * 32 + Lg * 8;
        qh[kc].u = *(const u32x4*)&qhi[o];
        ql[kc].u = *(const u32x4*)&qlo[o];
    }
    const fx2 ci = *(const fx2*)&coords[((size_t)b * Nc + i) * 2];
    __syncthreads();

    char* eb = sm.p.escr + w * 2304;       // 16 rows x 144 B
    fx4 oacc[4] = {};
    float m_r = -INFINITY, l_r = 0.f;

    for (int jt = 0; jt < 16; ++jt) {
        const int jbase = jt * 64;

        // V tile -> regs (issue early; written to LDS after barrier)
        u32x4 vsh[2], vsl[2];
        #pragma unroll
        for (int it = 0; it < 2; ++it) {
            const int s = tid + it * 256;
            const int l = s & 63;
            const int dd = ((s >> 7) << 4) + (l & 15);
            const int jo = jbase + ((s >> 6) & 1) * 32 + ((l >> 4) << 3);
            const size_t off = ((size_t)bh * Dc + dd) * Nc + jo;
            vsh[it] = *(const u32x4*)&vThi[off];
            vsl[it] = *(const u32x4*)&vTlo[off];
        }

        // QK^T (swapped: A = K rows j, B = Q cols i)
        fx4 acc[4] = {};
        #pragma unroll
        for (int kc = 0; kc < 2; ++kc) {
            Frag kh[4], kl[4];
            #pragma unroll
            for (int cg = 0; cg < 4; ++cg) {
                const size_t o = ((size_t)bh * Nc + jbase + cg * 16 + Lr) * 64 + kc * 32 + Lg * 8;
                kh[cg].u = *(const u32x4*)&khi[o];
                kl[cg].u = *(const u32x4*)&klo[o];
            }
            #pragma unroll
            for (int cg = 0; cg < 4; ++cg) {
                acc[cg] = __builtin_amdgcn_mfma_f32_16x16x32_bf16(kh[cg].s, qh[kc].s, acc[cg], 0, 0, 0);
                acc[cg] = __builtin_amdgcn_mfma_f32_16x16x32_bf16(kl[cg].s, qh[kc].s, acc[cg], 0, 0, 0);
                acc[cg] = __builtin_amdgcn_mfma_f32_16x16x32_bf16(kh[cg].s, ql[kc].s, acc[cg], 0, 0, 0);
            }
        }

        // spatial PL-MLP + combine
        float sv[16];
        #pragma unroll
        for (int cg = 0; cg < 4; ++cg) {
            #pragma unroll
            for (int r = 0; r < 4; ++r) {
                const fx2 cj = cjs[jbase + cg * 16 + Lg4 + r];
                const float dx = ci[0] - cj[0], dy = ci[1] - cj[1];
                const float dist = sqrtf(fmaf(dx, dx, fmaf(dy, dy, 1e-6f)));
                int bin = (int)(dist * (2048.0f / 1.41422f));
                bin = (bin > 2047) ? 2047 : bin;
                const fx2 ab = abt[luts[bin]];
                sv[cg * 4 + r] = fmaf(acc[cg][r], 0.125f, fmaf(ab[0], dist, ab[1]));
            }
        }

        // tile max + e + tile sum (per q-row Lr, uniform across Lg)
        float tm = sv[0];
        #pragma unroll
        for (int e = 1; e < 16; ++e) tm = fmaxf(tm, sv[e]);
        tm = fmaxf(tm, __shfl_xor(tm, 16));
        tm = fmaxf(tm, __shfl_xor(tm, 32));

        float ts = 0.f;
        #pragma unroll
        for (int e = 0; e < 16; ++e) { sv[e] = __expf(sv[e] - tm); ts += sv[e]; }
        ts += __shfl_xor(ts, 16);
        ts += __shfl_xor(ts, 32);

        if (Lg == 0) mT[((size_t)bh * Nc + i) * 16 + jt] = tm;

        __syncthreads();   // all waves done reading sm.p from jt-1
        #pragma unroll
        for (int it = 0; it < 2; ++it) {
            const int s = tid + it * 256;
            sm.p.vh[s] = vsh[it];
            sm.p.vl[s] = vsl[it];
        }
        // e permute scratch: row Lr (stride 144B), chunk c = cg*4+Lg (8B)
        // -> natural j order within the row (j = c*4 + r)
        #pragma unroll
        for (int cg = 0; cg < 4; ++cg) {
            H4 pk;
            #pragma unroll
            for (int r = 0; r < 4; ++r) pk.h[r] = (_Float16)sv[cg * 4 + r];
            *(u32x2*)(eb + Lr * 144 + (cg * 4 + Lg) * 8) = pk.d;
        }
        __syncthreads();   // V + e scratch visible

        // online rescale (row stats live in lane Lr == row; acc rows = Lg4+r)
        const float mnew = fmaxf(m_r, tm);
        const float facc = __expf(m_r - mnew);
        const float ftile = __expf(tm - mnew);
        l_r = l_r * facc + ts * ftile;
        m_r = mnew;
        #pragma unroll
        for (int r = 0; r < 4; ++r) {
            const float fr = __shfl(facc, Lg4 + r);
            #pragma unroll
            for (int dg = 0; dg < 4; ++dg) oacc[dg][r] *= fr;
        }
        const _Float16 fh = (_Float16)ftile;   // applies to A-frag rows = Lr

        const size_t ebase_g = (size_t)((bh * 16 + jt) * 2) * 32768 + (size_t)i * 32 + Lg * 8;
        #pragma unroll
        for (int kc = 0; kc < 2; ++kc) {
            Frag eA;
            eA.u = *(const u32x4*)(eb + Lr * 144 + kc * 64 + Lg * 16);
            *(u32x4*)&e_ws[ebase_g + (size_t)kc * 32768] = eA.u;   // natural j order
            Frag pa;
            pa.f16 = eA.f16 * fh;
            #pragma unroll
            for (int dg = 0; dg < 4; ++dg) {
                Frag vh_, vl_;
                vh_.u = sm.p.vh[(dg * 2 + kc) * 64 + L];
                vl_.u = sm.p.vl[(dg * 2 + kc) * 64 + L];
                oacc[dg] = __builtin_amdgcn_mfma_f32_16x16x32_f16(pa.f16, vh_.f16, oacc[dg], 0, 0, 0);
                oacc[dg] = __builtin_amdgcn_mfma_f32_16x16x32_f16(pa.f16, vl_.f16, oacc[dg], 0, 0, 0);
            }
        }
    }

    const float il = 1.0f / l_r;
    if (Lg == 0) *(fx2*)&mlfin[2 * ((size_t)bh * Nc + i)] = fx2{m_r, il};

    // il for accumulator rows via lane transpose
    float il4[4];
    #pragma unroll
    for (int r = 0; r < 4; ++r) il4[r] = __shfl(il, Lg4 + r);

    __syncthreads();   // done with sm.p everywhere
    #pragma unroll
    for (int dg = 0; dg < 4; ++dg)
        #pragma unroll
        for (int r = 0; r < 4; ++r)
            sm.scr[(w * 16 + Lg4 + r) * 68 + dg * 16 + Lr] = oacc[dg][r] * il4[r];
    __syncthreads();

    #pragma unroll
    for (int it = 0; it < 2; ++it) {
        const int lin = tid + it * 256;
        const int row = lin >> 3, d0 = (lin & 7) << 3;
        float vv[8];
        #pragma unroll
        for (int e = 0; e < 8; ++e) vv[e] = sm.scr[row * 68 + d0 + e];
        u32x4 hi, lo; split8(vv, hi, lo);
        const size_t o = ((size_t)b * Nc + i0 + row) * Cc + h * Dc + d0;
        *(u32x4*)&Hphi[o] = hi;
        *(u32x4*)&Hplo[o] = lo;
    }
}

// ---------------------------------------------------------------------------
// norm: attn[row][j] = e_ws * exp(m_t - m_row) * il. Pure streaming.
// ---------------------------------------------------------------------------
__global__ __launch_bounds__(256) void norm_kernel(
    const unsigned short* __restrict__ e_ws,
    const float* __restrict__ mT, const float* __restrict__ mlfin,
    float* __restrict__ attn)
{
    const size_t t = (size_t)blockIdx.x * 256 + threadIdx.x;   // < 1572864
    const int blk = (int)(t >> 10);
    const int i = (int)(t & 1023);
    const int bh = blk >> 5;
    const int jt = (blk >> 1) & 15;
    const int kc = blk & 1;
    const size_t row = (size_t)bh * Nc + i;

    const fx2 mf = *(const fx2*)&mlfin[2 * row];
    const float mt = mT[row * 16 + jt];
    const float f = __expf(mt - mf[0]) * mf[1];

    const unsigned short* ep = &e_ws[(size_t)blk * 32768 + (size_t)i * 32];
    float* ap = &attn[row * Nc + jt * 64 + kc * 32];
    #pragma unroll
    for (int c = 0; c < 4; ++c) {
        Frag ev;
        ev.u = *(const u32x4*)&ep[c * 8];
        fx4 o0, o1;
        o0[0] = (float)ev.f16[0] * f; o0[1] = (float)ev.f16[1] * f;
        o0[2] = (float)ev.f16[2] * f; o0[3] = (float)ev.f16[3] * f;
        o1[0] = (float)ev.f16[4] * f; o1[1] = (float)ev.f16[5] * f;
        o1[2] = (float)ev.f16[6] * f; o1[3] = (float)ev.f16[7] * f;
        *(fx4*)&ap[c * 8] = o0;
        *(fx4*)&ap[c * 8 + 4] = o1;
    }
}

// ---------------------------------------------------------------------------
extern "C" void kernel_launch(void* const* d_in, const int* in_sizes, int n_in,
                              void* d_out, int out_size, void* d_ws, size_t ws_size,
                              hipStream_t stream)
{
    (void)in_sizes; (void)n_in; (void)out_size; (void)ws_size;

    const float* x      = (const float*)d_in[0];
    const float* coords = (const float*)d_in[1];
    const float* Wq = (const float*)d_in[2];  const float* bq = (const float*)d_in[3];
    const float* Wk = (const float*)d_in[4];  const float* bk = (const float*)d_in[5];
    const float* Wv = (const float*)d_in[6];  const float* bv = (const float*)d_in[7];
    const float* Wo = (const float*)d_in[8];  const float* bo = (const float*)d_in[9];
    const float* Wd1 = (const float*)d_in[10]; const float* bd1 = (const float*)d_in[11];
    const float* Wd2 = (const float*)d_in[12]; const float* bd2 = (const float*)d_in[13];

    float* out_main = (float*)d_out;            // [B,N,C]
    float* attn     = out_main + QKV_ELEMS;     // [B,H,N,N]

    uint8_t* wsb = (uint8_t*)d_ws;
    const size_t SZ_BF = (size_t)BHc * Nc * Dc * 2;          // 6,291,456 B
    const size_t SZ_W4 = (size_t)4 * 768 * 768 * 2;          // 4,718,592 B
    unsigned short* qhi  = (unsigned short*)(wsb + 0 * SZ_BF);
    unsigned short* qlo  = (unsigned short*)(wsb + 1 * SZ_BF);
    unsigned short* khi  = (unsigned short*)(wsb + 2 * SZ_BF);
    unsigned short* klo  = (unsigned short*)(wsb + 3 * SZ_BF);
    unsigned short* vThi = (unsigned short*)(wsb + 4 * SZ_BF);
    unsigned short* vTlo = (unsigned short*)(wsb + 5 * SZ_BF);
    unsigned short* xhi  = (unsigned short*)(wsb + 6 * SZ_BF); // reused as Hphi
    unsigned short* xlo  = (unsigned short*)(wsb + 7 * SZ_BF); // reused as Hplo
    unsigned short* Thi  = (unsigned short*)(wsb + 8 * SZ_BF);
    unsigned short* Tlo  = (unsigned short*)(wsb + 8 * SZ_BF + SZ_W4);
    uint8_t* base8 = wsb + 8 * SZ_BF + 2 * SZ_W4;
    float* abPack = (float*)base8;                            // 408 floats
    unsigned char* lut = (unsigned char*)(base8 + 4096);      // 2048 B
    float* mT    = (float*)(base8 + 8192);                    // 48*1024*16 f32 = 3 MB
    float* mlfin = mT + (size_t)BHc * Nc * 16;                // 48*1024*2 f32
    unsigned short* e_ws = (unsigned short*)(mlfin + (size_t)BHc * Nc * 2); // 100.7 MB

    prep_w_kernel<<<dim3(12, 12, 4), 256, 0, stream>>>(Wq, Wk, Wv, Wo, Thi, Tlo);
    prep_tables_kernel<<<1, 256, 0, stream>>>(Wd1, bd1, Wd2, bd2, abPack, lut);
    split_x_kernel<<<dim3(1536), 256, 0, stream>>>(x, xhi, xlo);

    qkv_kernel<<<dim3(12, 64, 3), 256, 0, stream>>>(
        xhi, xlo, Thi, Tlo, bq, bk, bv,
        qhi, qlo, khi, klo, vThi, vTlo);

    attn_flash_kernel<<<dim3(16, 48), 256, 0, stream>>>(
        qhi, qlo, khi, klo, vThi, vTlo, coords, abPack, lut,
        e_ws, mT, mlfin, xhi, xlo);

    norm_kernel<<<dim3(6144), 256, 0, stream>>>(e_ws, mT, mlfin, attn);

    gemm_mfma_kernel<2><<<dim3(12, 64), 256, 0, stream>>>(
        xhi, xlo, Thi + (size_t)3 * 768 * 768, Tlo + (size_t)3 * 768 * 768,
        bo, out_main);
}

// Round 10
// 417.484 us; speedup vs baseline: 1.1068x; 1.0174x over previous
//
#include <hip/hip_runtime.h>
#include <cstddef>
#include <cstdint>

#define Bc 4
#define Nc 1024
#define Cc 768
#define Hc 12
#define Dc 64
#define BHc 48
#define QKV_ELEMS ((size_t)Bc * Nc * Cc)   // 3145728

typedef __attribute__((ext_vector_type(4))) unsigned int u32x4;
typedef __attribute__((ext_vector_type(2))) unsigned int u32x2;
typedef __attribute__((ext_vector_type(8))) short s16x8;
typedef __attribute__((ext_vector_type(8))) _Float16 h16x8;
typedef __attribute__((ext_vector_type(4))) float fx4;
typedef __attribute__((ext_vector_type(2))) float fx2;

union Frag { u32x4 u; s16x8 s; h16x8 f16; unsigned short h[8]; };
union H4 { u32x2 d; _Float16 h[4]; };

__device__ inline unsigned short f2bf(float x) {
    union { float f; uint32_t u; } c; c.f = x;
    return (unsigned short)((c.u + 0x7FFFu + ((c.u >> 16) & 1u)) >> 16);
}
__device__ inline float bf2f(unsigned short b) {
    union { uint32_t u; float f; } c; c.u = ((uint32_t)b) << 16;
    return c.f;
}
__device__ inline void split8(const float* v, u32x4& hi, u32x4& lo) {
    Frag fh, fl;
    #pragma unroll
    for (int e = 0; e < 8; ++e) {
        const unsigned short hb = f2bf(v[e]);
        fh.h[e] = hb;
        fl.h[e] = f2bf(v[e] - bf2f(hb));
    }
    hi = fh.u; lo = fl.u;
}
__device__ inline void split8h(const float* v, u32x4& hi, u32x4& lo) {
    Frag fh, fl;
    #pragma unroll
    for (int e = 0; e < 8; ++e) {
        const _Float16 hb = (_Float16)v[e];
        fh.f16[e] = hb;
        fl.f16[e] = (_Float16)(v[e] - (float)hb);
    }
    hi = fh.u; lo = fl.u;
}

// ---------------------------------------------------------------------------
// prep_w: Wt_hi/lo[mat][n][k] = split(W[k][n])  (bf16 hi/lo)
// ---------------------------------------------------------------------------
__global__ __launch_bounds__(256) void prep_w_kernel(
    const float* __restrict__ Wq, const float* __restrict__ Wk,
    const float* __restrict__ Wv, const float* __restrict__ Wo,
    unsigned short* __restrict__ Thi, unsigned short* __restrict__ Tlo)
{
    __shared__ float scr[64 * 65];
    const int mat = blockIdx.z;
    const float* W = (mat == 0) ? Wq : (mat == 1) ? Wk : (mat == 2) ? Wv : Wo;
    const int k0 = blockIdx.y * 64, n0 = blockIdx.x * 64;
    const int tid = threadIdx.x;

    #pragma unroll
    for (int it = 0; it < 4; ++it) {
        const int lin = tid + it * 256;
        const int r = lin >> 4, c4 = (lin & 15) << 2;
        const fx4 v = *(const fx4*)&W[(size_t)(k0 + r) * 768 + n0 + c4];
        scr[r * 65 + c4 + 0] = v[0]; scr[r * 65 + c4 + 1] = v[1];
        scr[r * 65 + c4 + 2] = v[2]; scr[r * 65 + c4 + 3] = v[3];
    }
    __syncthreads();
    unsigned short* th = Thi + (size_t)mat * 768 * 768;
    unsigned short* tl = Tlo + (size_t)mat * 768 * 768;
    #pragma unroll
    for (int it = 0; it < 16; ++it) {
        const int lin = tid + it * 256;
        const int n = lin >> 6, kq = lin & 63;
        const float val = scr[kq * 65 + n];
        const size_t o = (size_t)(n0 + n) * 768 + k0 + kq;
        const unsigned short hb = f2bf(val);
        th[o] = hb;
        tl[o] = f2bf(val - bf2f(hb));
    }
}

// ---------------------------------------------------------------------------
// prep_tables: PL (alpha,beta) per (segment, h) + 2048-bin u8 idx LUT.
// ---------------------------------------------------------------------------
__global__ __launch_bounds__(256) void prep_tables_kernel(
    const float* __restrict__ Wd1, const float* __restrict__ bd1,
    const float* __restrict__ Wd2, const float* __restrict__ bd2,
    float* __restrict__ abPack, unsigned char* __restrict__ lut)
{
    __shared__ float w1s[16], b1s[16], kn[16];
    __shared__ int rank[16];
    const int tid = threadIdx.x;
    if (tid < 16) {
        const float w1 = Wd1[tid], b1 = bd1[tid];
        w1s[tid] = w1; b1s[tid] = b1;
        kn[tid] = (w1 != 0.0f) ? (-b1 / w1) : INFINITY;
    }
    __syncthreads();
    if (tid < 16) {
        int rk = 0;
        for (int u = 0; u < 16; ++u) {
            const float ku = kn[u], km = kn[tid];
            if (ku < km || (ku == km && u < tid)) ++rk;
        }
        rank[tid] = rk;
    }
    __syncthreads();
    if (tid < 17 * 12) {
        const int s = tid / 12, h = tid % 12;
        float a = 0.0f, be = bd2[h];
        for (int u = 0; u < 16; ++u) {
            const float w1 = w1s[u], b1 = b1s[u];
            bool act;
            if (w1 > 0.0f)      act = (rank[u] < s);
            else if (w1 < 0.0f) act = (rank[u] >= s);
            else                act = (b1 > 0.0f);
            if (act) {
                const float w2 = Wd2[u * 12 + h];
                a  += w2 * w1;
                be += w2 * b1;
            }
        }
        abPack[tid * 2 + 0] = a;
        abPack[tid * 2 + 1] = be;
    }
    for (int b = tid; b < 2048; b += 256) {
        const float rep = (b + 0.5f) * (1.41422f / 2048.0f);
        int cnt = 0;
        for (int t = 0; t < 16; ++t) cnt += (rep > kn[t]) ? 1 : 0;
        lut[b] = (unsigned char)cnt;
    }
}

// ---------------------------------------------------------------------------
// split_x: x fp32 -> xhi/xlo bf16 row-major
// ---------------------------------------------------------------------------
__global__ __launch_bounds__(256) void split_x_kernel(
    const float* __restrict__ x, unsigned short* __restrict__ xhi,
    unsigned short* __restrict__ xlo)
{
    const size_t t = (size_t)blockIdx.x * 256 + threadIdx.x;
    float vv[8];
    const fx4 a = *(const fx4*)&x[t * 8];
    const fx4 b = *(const fx4*)&x[t * 8 + 4];
    vv[0]=a[0]; vv[1]=a[1]; vv[2]=a[2]; vv[3]=a[3];
    vv[4]=b[0]; vv[5]=b[1]; vv[6]=b[2]; vv[7]=b[3];
    u32x4 hi, lo; split8(vv, hi, lo);
    *(u32x4*)&xhi[t * 8] = hi;
    *(u32x4*)&xlo[t * 8] = lo;
}

// ---------------------------------------------------------------------------
// gemm_mfma: out = A[4096x768] @ W[768x768] + bias, bf16x3 MFMA.
// OMODE 0: bf16 hi/lo head layout [bh][n][d] (q,k)
// OMODE 1: f16 hi/lo vT [bh][d][n] (v)
// OMODE 2: fp32 row-major (final out)
// Launched SEPARATELY per matrix so only one W is L2-resident at a time.
// ---------------------------------------------------------------------------
struct SmemG { u32x4 ah[512]; u32x4 al[512]; u32x4 bh[512]; u32x4 bl[512]; };
struct SmemT { float scr[64 * 68]; };
union SmemU { SmemG g; SmemT t; };

template<int OMODE>
__global__ __launch_bounds__(256) void gemm_mfma_kernel(
    const unsigned short* __restrict__ Ahi, const unsigned short* __restrict__ Alo,
    const unsigned short* __restrict__ Bhi, const unsigned short* __restrict__ Blo,
    const float* __restrict__ bias,
    float* __restrict__ outF,
    unsigned short* __restrict__ Ohi, unsigned short* __restrict__ Olo)
{
    __shared__ SmemU sm;
    const int tid = threadIdx.x;
    const int w = tid >> 6, L = tid & 63;
    const int Lr = L & 15, Lg = L >> 4;
    const int m0 = blockIdx.y * 64, n0 = blockIdx.x * 64;

    fx4 acc[2][2] = {};

    for (int kk = 0; kk < 768; kk += 64) {
        #pragma unroll
        for (int it = 0; it < 2; ++it) {
            const int slot = tid + it * 256;
            const int s = slot >> 6, l = slot & 63;
            const int row = m0 + ((s >> 1) << 4) + (l & 15);
            const int kb = kk + ((s & 1) << 5) + ((l >> 4) << 3);
            sm.g.ah[slot] = *(const u32x4*)&Ahi[(size_t)row * 768 + kb];
            sm.g.al[slot] = *(const u32x4*)&Alo[(size_t)row * 768 + kb];
            const int col = n0 + ((s >> 1) << 4) + (l & 15);
            sm.g.bh[slot] = *(const u32x4*)&Bhi[(size_t)col * 768 + kb];
            sm.g.bl[slot] = *(const u32x4*)&Blo[(size_t)col * 768 + kb];
        }
        __syncthreads();
        #pragma unroll
        for (int kc = 0; kc < 2; ++kc) {
            Frag ah[2], al[2], bh[2], bl[2];
            #pragma unroll
            for (int mm = 0; mm < 2; ++mm) {
                const int rg = (w >> 1) * 2 + mm;
                ah[mm].u = sm.g.ah[(rg * 2 + kc) * 64 + L];
                al[mm].u = sm.g.al[(rg * 2 + kc) * 64 + L];
            }
            #pragma unroll
            for (int nn = 0; nn < 2; ++nn) {
                const int cg = (w & 1) * 2 + nn;
                bh[nn].u = sm.g.bh[(cg * 2 + kc) * 64 + L];
                bl[nn].u = sm.g.bl[(cg * 2 + kc) * 64 + L];
            }
            #pragma unroll
            for (int mm = 0; mm < 2; ++mm)
                #pragma unroll
                for (int nn = 0; nn < 2; ++nn) {
                    acc[mm][nn] = __builtin_amdgcn_mfma_f32_16x16x32_bf16(ah[mm].s, bh[nn].s, acc[mm][nn], 0, 0, 0);
                    acc[mm][nn] = __builtin_amdgcn_mfma_f32_16x16x32_bf16(ah[mm].s, bl[nn].s, acc[mm][nn], 0, 0, 0);
                    acc[mm][nn] = __builtin_amdgcn_mfma_f32_16x16x32_bf16(al[mm].s, bh[nn].s, acc[mm][nn], 0, 0, 0);
                }
        }
        __syncthreads();
    }

    #pragma unroll
    for (int mm = 0; mm < 2; ++mm) {
        const int rl = (w >> 1) * 32 + mm * 16 + Lg * 4;
        #pragma unroll
        for (int nn = 0; nn < 2; ++nn) {
            const int cl = (w & 1) * 32 + nn * 16 + Lr;
            const float bs = bias[n0 + cl];
            #pragma unroll
            for (int r = 0; r < 4; ++r)
                sm.t.scr[(rl + r) * 68 + cl] = acc[mm][nn][r] + bs;
        }
    }
    __syncthreads();

    if (OMODE == 0) {
        const int h = n0 >> 6;
        #pragma unroll
        for (int it = 0; it < 2; ++it) {
            const int t = tid + it * 256;
            const int r = t >> 3, d0 = (t & 7) << 3;
            float vv[8];
            #pragma unroll
            for (int e = 0; e < 8; ++e) vv[e] = sm.t.scr[r * 68 + d0 + e];
            u32x4 hi, lo; split8(vv, hi, lo);
            const int rg = m0 + r, b = rg >> 10, nloc = rg & 1023;
            const size_t o = (((size_t)(b * Hc + h) * Nc + nloc) << 6) + d0;
            *(u32x4*)&Ohi[o] = hi;
            *(u32x4*)&Olo[o] = lo;
        }
    } else if (OMODE == 1) {
        const int b = m0 >> 10, h = n0 >> 6, nbase = m0 & 1023;
        #pragma unroll
        for (int it = 0; it < 2; ++it) {
            const int t = tid + it * 256;
            const int dd = t >> 3, j0 = (t & 7) << 3;
            float vv[8];
            #pragma unroll
            for (int e = 0; e < 8; ++e) vv[e] = sm.t.scr[(j0 + e) * 68 + dd];
            u32x4 hi, lo; split8h(vv, hi, lo);   // f16 hi/lo for PV
            const size_t o = (size_t)((b * Hc + h) * Dc + dd) * Nc + nbase + j0;
            *(u32x4*)&Ohi[o] = hi;
            *(u32x4*)&Olo[o] = lo;
        }
    } else {
        #pragma unroll
        for (int it = 0; it < 4; ++it) {
            const int lin = tid + it * 256;
            const int r = lin >> 4, c4 = (lin & 15) << 2;
            const fx4 v = *(const fx4*)&sm.t.scr[r * 68 + c4];
            *(fx4*)&outF[(size_t)(m0 + r) * 768 + n0 + c4] = v;
        }
    }
}

// ---------------------------------------------------------------------------
// attn_flash: single pass over jt with online rescaling (r9 numerics).
// FIX vs r9: e-scratch stored in lane-LINEAR read order -> the b128 e reads
// are conflict-free (was 8-way: word-bank 4(Lr+Lg) mod 32 collided).
// Granule g = cg*4+Lg of row Lr lives at:
//   (g>>3)*1024 + (((g&7)>>1)*16 + Lr)*16 + (g&1)*8
// Read: eb + kc*1024 + L*16  (L = Lg*16+Lr), identical j-order as before.
// ---------------------------------------------------------------------------
union FlashSmem {
    struct { u32x4 vh[512]; u32x4 vl[512]; char escr[4 * 2048]; } p;  // 24576 B
    float scr[64 * 68];                                               // 17408 B
};

__global__ __launch_bounds__(256) void attn_flash_kernel(
    const unsigned short* __restrict__ qhi, const unsigned short* __restrict__ qlo,
    const unsigned short* __restrict__ khi, const unsigned short* __restrict__ klo,
    const unsigned short* __restrict__ vThi, const unsigned short* __restrict__ vTlo,
    const float* __restrict__ coords,
    const float* __restrict__ abPack, const unsigned char* __restrict__ lutg,
    unsigned short* __restrict__ e_ws, float* __restrict__ mT,
    float* __restrict__ mlfin,
    unsigned short* __restrict__ Hphi, unsigned short* __restrict__ Hplo)
{
    __shared__ FlashSmem sm;
    __shared__ fx2 cjs[1024];
    __shared__ unsigned char luts[2048];
    __shared__ fx2 abt[17];

    const int tid = threadIdx.x;
    const int w = tid >> 6, L = tid & 63;
    const int Lr = L & 15, Lg = L >> 4;
    const int bh = blockIdx.y, b = bh / Hc, h = bh % Hc;
    const int i0 = blockIdx.x * 64;
    const int i = i0 + w * 16 + Lr;
    const int Lg4 = Lg * 4;

    if (tid < 17) abt[tid] = ((const fx2*)abPack)[tid * Hc + h];
    for (int t = tid; t < 512; t += 256)
        ((uint32_t*)luts)[t] = ((const uint32_t*)lutg)[t];
    for (int t = tid; t < 1024; t += 256)
        cjs[t] = *(const fx2*)&coords[((size_t)b * Nc + t) * 2];

    Frag qh[2], ql[2];
    #pragma unroll
    for (int kc = 0; kc < 2; ++kc) {
        const size_t o = ((size_t)bh * Nc + i) * 64 + kc * 32 + Lg * 8;
        qh[kc].u = *(const u32x4*)&qhi[o];
        ql[kc].u = *(const u32x4*)&qlo[o];
    }
    const fx2 ci = *(const fx2*)&coords[((size_t)b * Nc + i) * 2];
    __syncthreads();

    char* eb = sm.p.escr + w * 2048;       // 2 kc x 1024 B, lane-linear reads
    fx4 oacc[4] = {};
    float m_r = -INFINITY, l_r = 0.f;

    for (int jt = 0; jt < 16; ++jt) {
        const int jbase = jt * 64;

        // V tile -> regs (issue early; written to LDS after barrier)
        u32x4 vsh[2], vsl[2];
        #pragma unroll
        for (int it = 0; it < 2; ++it) {
            const int s = tid + it * 256;
            const int l = s & 63;
            const int dd = ((s >> 7) << 4) + (l & 15);
            const int jo = jbase + ((s >> 6) & 1) * 32 + ((l >> 4) << 3);
            const size_t off = ((size_t)bh * Dc + dd) * Nc + jo;
            vsh[it] = *(const u32x4*)&vThi[off];
            vsl[it] = *(const u32x4*)&vTlo[off];
        }

        // QK^T (swapped: A = K rows j, B = Q cols i)
        fx4 acc[4] = {};
        #pragma unroll
        for (int kc = 0; kc < 2; ++kc) {
            Frag kh[4], kl[4];
            #pragma unroll
            for (int cg = 0; cg < 4; ++cg) {
                const size_t o = ((size_t)bh * Nc + jbase + cg * 16 + Lr) * 64 + kc * 32 + Lg * 8;
                kh[cg].u = *(const u32x4*)&khi[o];
                kl[cg].u = *(const u32x4*)&klo[o];
            }
            #pragma unroll
            for (int cg = 0; cg < 4; ++cg) {
                acc[cg] = __builtin_amdgcn_mfma_f32_16x16x32_bf16(kh[cg].s, qh[kc].s, acc[cg], 0, 0, 0);
                acc[cg] = __builtin_amdgcn_mfma_f32_16x16x32_bf16(kl[cg].s, qh[kc].s, acc[cg], 0, 0, 0);
                acc[cg] = __builtin_amdgcn_mfma_f32_16x16x32_bf16(kh[cg].s, ql[kc].s, acc[cg], 0, 0, 0);
            }
        }

        // spatial PL-MLP + combine
        float sv[16];
        #pragma unroll
        for (int cg = 0; cg < 4; ++cg) {
            #pragma unroll
            for (int r = 0; r < 4; ++r) {
                const fx2 cj = cjs[jbase + cg * 16 + Lg4 + r];
                const float dx = ci[0] - cj[0], dy = ci[1] - cj[1];
                const float dist = sqrtf(fmaf(dx, dx, fmaf(dy, dy, 1e-6f)));
                int bin = (int)(dist * (2048.0f / 1.41422f));
                bin = (bin > 2047) ? 2047 : bin;
                const fx2 ab = abt[luts[bin]];
                sv[cg * 4 + r] = fmaf(acc[cg][r], 0.125f, fmaf(ab[0], dist, ab[1]));
            }
        }

        // tile max + e + tile sum (per q-row Lr, uniform across Lg)
        float tm = sv[0];
        #pragma unroll
        for (int e = 1; e < 16; ++e) tm = fmaxf(tm, sv[e]);
        tm = fmaxf(tm, __shfl_xor(tm, 16));
        tm = fmaxf(tm, __shfl_xor(tm, 32));

        float ts = 0.f;
        #pragma unroll
        for (int e = 0; e < 16; ++e) { sv[e] = __expf(sv[e] - tm); ts += sv[e]; }
        ts += __shfl_xor(ts, 16);
        ts += __shfl_xor(ts, 32);

        if (Lg == 0) mT[((size_t)bh * Nc + i) * 16 + jt] = tm;

        __syncthreads();   // all waves done reading sm.p from jt-1
        #pragma unroll
        for (int it = 0; it < 2; ++it) {
            const int s = tid + it * 256;
            sm.p.vh[s] = vsh[it];
            sm.p.vl[s] = vsl[it];
        }
        // e scratch write: granule g = cg*4+Lg of row Lr, linear-read layout
        #pragma unroll
        for (int cg = 0; cg < 4; ++cg) {
            H4 pk;
            #pragma unroll
            for (int r = 0; r < 4; ++r) pk.h[r] = (_Float16)sv[cg * 4 + r];
            const int g = cg * 4 + Lg;
            const int waddr = ((g >> 3) << 10) + (((((g & 7) >> 1) << 4) + Lr) << 4) + ((g & 1) << 3);
            *(u32x2*)(eb + waddr) = pk.d;
        }
        __syncthreads();   // V + e scratch visible

        // online rescale (row stats live in lane Lr == row; acc rows = Lg4+r)
        const float mnew = fmaxf(m_r, tm);
        const float facc = __expf(m_r - mnew);
        const float ftile = __expf(tm - mnew);
        l_r = l_r * facc + ts * ftile;
        m_r = mnew;
        #pragma unroll
        for (int r = 0; r < 4; ++r) {
            const float fr = __shfl(facc, Lg4 + r);
            #pragma unroll
            for (int dg = 0; dg < 4; ++dg) oacc[dg][r] *= fr;
        }
        const _Float16 fh = (_Float16)ftile;   // applies to A-frag rows = Lr

        const size_t ebase_g = (size_t)((bh * 16 + jt) * 2) * 32768 + (size_t)i * 32 + Lg * 8;
        #pragma unroll
        for (int kc = 0; kc < 2; ++kc) {
            Frag eA;
            eA.u = *(const u32x4*)(eb + kc * 1024 + (L << 4));   // lane-linear
            *(u32x4*)&e_ws[ebase_g + (size_t)kc * 32768] = eA.u; // natural j order
            Frag pa;
            pa.f16 = eA.f16 * fh;
            #pragma unroll
            for (int dg = 0; dg < 4; ++dg) {
                Frag vh_, vl_;
                vh_.u = sm.p.vh[(dg * 2 + kc) * 64 + L];
                vl_.u = sm.p.vl[(dg * 2 + kc) * 64 + L];
                oacc[dg] = __builtin_amdgcn_mfma_f32_16x16x32_f16(pa.f16, vh_.f16, oacc[dg], 0, 0, 0);
                oacc[dg] = __builtin_amdgcn_mfma_f32_16x16x32_f16(pa.f16, vl_.f16, oacc[dg], 0, 0, 0);
            }
        }
    }

    const float il = 1.0f / l_r;
    if (Lg == 0) *(fx2*)&mlfin[2 * ((size_t)bh * Nc + i)] = fx2{m_r, il};

    // il for accumulator rows via lane transpose
    float il4[4];
    #pragma unroll
    for (int r = 0; r < 4; ++r) il4[r] = __shfl(il, Lg4 + r);

    __syncthreads();   // done with sm.p everywhere
    #pragma unroll
    for (int dg = 0; dg < 4; ++dg)
        #pragma unroll
        for (int r = 0; r < 4; ++r)
            sm.scr[(w * 16 + Lg4 + r) * 68 + dg * 16 + Lr] = oacc[dg][r] * il4[r];
    __syncthreads();

    #pragma unroll
    for (int it = 0; it < 2; ++it) {
        const int lin = tid + it * 256;
        const int row = lin >> 3, d0 = (lin & 7) << 3;
        float vv[8];
        #pragma unroll
        for (int e = 0; e < 8; ++e) vv[e] = sm.scr[row * 68 + d0 + e];
        u32x4 hi, lo; split8(vv, hi, lo);
        const size_t o = ((size_t)b * Nc + i0 + row) * Cc + h * Dc + d0;
        *(u32x4*)&Hphi[o] = hi;
        *(u32x4*)&Hplo[o] = lo;
    }
}

// ---------------------------------------------------------------------------
// norm: attn[row][j] = e_ws * exp(m_t - m_row) * il. Pure streaming.
// ---------------------------------------------------------------------------
__global__ __launch_bounds__(256) void norm_kernel(
    const unsigned short* __restrict__ e_ws,
    const float* __restrict__ mT, const float* __restrict__ mlfin,
    float* __restrict__ attn)
{
    const size_t t = (size_t)blockIdx.x * 256 + threadIdx.x;   // < 1572864
    const int blk = (int)(t >> 10);
    const int i = (int)(t & 1023);
    const int bh = blk >> 5;
    const int jt = (blk >> 1) & 15;
    const int kc = blk & 1;
    const size_t row = (size_t)bh * Nc + i;

    const fx2 mf = *(const fx2*)&mlfin[2 * row];
    const float mt = mT[row * 16 + jt];
    const float f = __expf(mt - mf[0]) * mf[1];

    const unsigned short* ep = &e_ws[(size_t)blk * 32768 + (size_t)i * 32];
    float* ap = &attn[row * Nc + jt * 64 + kc * 32];
    #pragma unroll
    for (int c = 0; c < 4; ++c) {
        Frag ev;
        ev.u = *(const u32x4*)&ep[c * 8];
        fx4 o0, o1;
        o0[0] = (float)ev.f16[0] * f; o0[1] = (float)ev.f16[1] * f;
        o0[2] = (float)ev.f16[2] * f; o0[3] = (float)ev.f16[3] * f;
        o1[0] = (float)ev.f16[4] * f; o1[1] = (float)ev.f16[5] * f;
        o1[2] = (float)ev.f16[6] * f; o1[3] = (float)ev.f16[7] * f;
        *(fx4*)&ap[c * 8] = o0;
        *(fx4*)&ap[c * 8 + 4] = o1;
    }
}

// ---------------------------------------------------------------------------
extern "C" void kernel_launch(void* const* d_in, const int* in_sizes, int n_in,
                              void* d_out, int out_size, void* d_ws, size_t ws_size,
                              hipStream_t stream)
{
    (void)in_sizes; (void)n_in; (void)out_size; (void)ws_size;

    const float* x      = (const float*)d_in[0];
    const float* coords = (const float*)d_in[1];
    const float* Wq = (const float*)d_in[2];  const float* bq = (const float*)d_in[3];
    const float* Wk = (const float*)d_in[4];  const float* bk = (const float*)d_in[5];
    const float* Wv = (const float*)d_in[6];  const float* bv = (const float*)d_in[7];
    const float* Wo = (const float*)d_in[8];  const float* bo = (const float*)d_in[9];
    const float* Wd1 = (const float*)d_in[10]; const float* bd1 = (const float*)d_in[11];
    const float* Wd2 = (const float*)d_in[12]; const float* bd2 = (const float*)d_in[13];

    float* out_main = (float*)d_out;            // [B,N,C]
    float* attn     = out_main + QKV_ELEMS;     // [B,H,N,N]

    uint8_t* wsb = (uint8_t*)d_ws;
    const size_t SZ_BF = (size_t)BHc * Nc * Dc * 2;          // 6,291,456 B
    const size_t SZ_W4 = (size_t)4 * 768 * 768 * 2;          // 4,718,592 B
    unsigned short* qhi  = (unsigned short*)(wsb + 0 * SZ_BF);
    unsigned short* qlo  = (unsigned short*)(wsb + 1 * SZ_BF);
    unsigned short* khi  = (unsigned short*)(wsb + 2 * SZ_BF);
    unsigned short* klo  = (unsigned short*)(wsb + 3 * SZ_BF);
    unsigned short* vThi = (unsigned short*)(wsb + 4 * SZ_BF);
    unsigned short* vTlo = (unsigned short*)(wsb + 5 * SZ_BF);
    unsigned short* xhi  = (unsigned short*)(wsb + 6 * SZ_BF); // reused as Hphi
    unsigned short* xlo  = (unsigned short*)(wsb + 7 * SZ_BF); // reused as Hplo
    unsigned short* Thi  = (unsigned short*)(wsb + 8 * SZ_BF);
    unsigned short* Tlo  = (unsigned short*)(wsb + 8 * SZ_BF + SZ_W4);
    uint8_t* base8 = wsb + 8 * SZ_BF + 2 * SZ_W4;
    float* abPack = (float*)base8;                            // 408 floats
    unsigned char* lut = (unsigned char*)(base8 + 4096);      // 2048 B
    float* mT    = (float*)(base8 + 8192);                    // 48*1024*16 f32 = 3 MB
    float* mlfin = mT + (size_t)BHc * Nc * 16;                // 48*1024*2 f32
    unsigned short* e_ws = (unsigned short*)(mlfin + (size_t)BHc * Nc * 2); // 100.7 MB

    prep_w_kernel<<<dim3(12, 12, 4), 256, 0, stream>>>(Wq, Wk, Wv, Wo, Thi, Tlo);
    prep_tables_kernel<<<1, 256, 0, stream>>>(Wd1, bd1, Wd2, bd2, abPack, lut);
    split_x_kernel<<<dim3(1536), 256, 0, stream>>>(x, xhi, xlo);

    dim3 gGemm(12, 64);
    gemm_mfma_kernel<0><<<gGemm, 256, 0, stream>>>(
        xhi, xlo, Thi + (size_t)0 * 768 * 768, Tlo + (size_t)0 * 768 * 768,
        bq, nullptr, qhi, qlo);
    gemm_mfma_kernel<0><<<gGemm, 256, 0, stream>>>(
        xhi, xlo, Thi + (size_t)1 * 768 * 768, Tlo + (size_t)1 * 768 * 768,
        bk, nullptr, khi, klo);
    gemm_mfma_kernel<1><<<gGemm, 256, 0, stream>>>(
        xhi, xlo, Thi + (size_t)2 * 768 * 768, Tlo + (size_t)2 * 768 * 768,
        bv, nullptr, vThi, vTlo);

    attn_flash_kernel<<<dim3(16, 48), 256, 0, stream>>>(
        qhi, qlo, khi, klo, vThi, vTlo, coords, abPack, lut,
        e_ws, mT, mlfin, xhi, xlo);

    norm_kernel<<<dim3(6144), 256, 0, stream>>>(e_ws, mT, mlfin, attn);

    gemm_mfma_kernel<2><<<gGemm, 256, 0, stream>>>(
        xhi, xlo, Thi + (size_t)3 * 768 * 768, Tlo + (size_t)3 * 768 * 768,
        bo, out_main, nullptr, nullptr);
}

// Round 11
// 393.349 us; speedup vs baseline: 1.1747x; 1.0614x over previous
//
#include <hip/hip_runtime.h>
#include <cstddef>
#include <cstdint>

#define Bc 4
#define Nc 1024
#define Cc 768
#define Hc 12
#define Dc 64
#define BHc 48
#define QKV_ELEMS ((size_t)Bc * Nc * Cc)   // 3145728

typedef __attribute__((ext_vector_type(4))) unsigned int u32x4;
typedef __attribute__((ext_vector_type(2))) unsigned int u32x2;
typedef __attribute__((ext_vector_type(8))) short s16x8;
typedef __attribute__((ext_vector_type(8))) _Float16 h16x8;
typedef __attribute__((ext_vector_type(4))) _Float16 h16x4;
typedef __attribute__((ext_vector_type(4))) float fx4;
typedef __attribute__((ext_vector_type(2))) float fx2;

union Frag { u32x4 u; s16x8 s; h16x8 f16; unsigned short h[8]; };
union H4b { u32x2 d; h16x4 h4; };

__device__ inline unsigned short f2bf(float x) {
    union { float f; uint32_t u; } c; c.f = x;
    return (unsigned short)((c.u + 0x7FFFu + ((c.u >> 16) & 1u)) >> 16);
}
__device__ inline float bf2f(unsigned short b) {
    union { uint32_t u; float f; } c; c.u = ((uint32_t)b) << 16;
    return c.f;
}
__device__ inline void split8(const float* v, u32x4& hi, u32x4& lo) {
    Frag fh, fl;
    #pragma unroll
    for (int e = 0; e < 8; ++e) {
        const unsigned short hb = f2bf(v[e]);
        fh.h[e] = hb;
        fl.h[e] = f2bf(v[e] - bf2f(hb));
    }
    hi = fh.u; lo = fl.u;
}
__device__ inline void split8h(const float* v, u32x4& hi, u32x4& lo) {
    Frag fh, fl;
    #pragma unroll
    for (int e = 0; e < 8; ++e) {
        const _Float16 hb = (_Float16)v[e];
        fh.f16[e] = hb;
        fl.f16[e] = (_Float16)(v[e] - (float)hb);
    }
    hi = fh.u; lo = fl.u;
}

// ---------------------------------------------------------------------------
// prep_w: Wt_hi/lo[mat][n][k] = split(W[k][n])  (bf16 hi/lo)
// ---------------------------------------------------------------------------
__global__ __launch_bounds__(256) void prep_w_kernel(
    const float* __restrict__ Wq, const float* __restrict__ Wk,
    const float* __restrict__ Wv, const float* __restrict__ Wo,
    unsigned short* __restrict__ Thi, unsigned short* __restrict__ Tlo)
{
    __shared__ float scr[64 * 65];
    const int mat = blockIdx.z;
    const float* W = (mat == 0) ? Wq : (mat == 1) ? Wk : (mat == 2) ? Wv : Wo;
    const int k0 = blockIdx.y * 64, n0 = blockIdx.x * 64;
    const int tid = threadIdx.x;

    #pragma unroll
    for (int it = 0; it < 4; ++it) {
        const int lin = tid + it * 256;
        const int r = lin >> 4, c4 = (lin & 15) << 2;
        const fx4 v = *(const fx4*)&W[(size_t)(k0 + r) * 768 + n0 + c4];
        scr[r * 65 + c4 + 0] = v[0]; scr[r * 65 + c4 + 1] = v[1];
        scr[r * 65 + c4 + 2] = v[2]; scr[r * 65 + c4 + 3] = v[3];
    }
    __syncthreads();
    unsigned short* th = Thi + (size_t)mat * 768 * 768;
    unsigned short* tl = Tlo + (size_t)mat * 768 * 768;
    #pragma unroll
    for (int it = 0; it < 16; ++it) {
        const int lin = tid + it * 256;
        const int n = lin >> 6, kq = lin & 63;
        const float val = scr[kq * 65 + n];
        const size_t o = (size_t)(n0 + n) * 768 + k0 + kq;
        const unsigned short hb = f2bf(val);
        th[o] = hb;
        tl[o] = f2bf(val - bf2f(hb));
    }
}

// ---------------------------------------------------------------------------
// prep_tables: PL (alpha,beta) per (segment, h) + 2048-bin u8 idx LUT.
// ---------------------------------------------------------------------------
__global__ __launch_bounds__(256) void prep_tables_kernel(
    const float* __restrict__ Wd1, const float* __restrict__ bd1,
    const float* __restrict__ Wd2, const float* __restrict__ bd2,
    float* __restrict__ abPack, unsigned char* __restrict__ lut)
{
    __shared__ float w1s[16], b1s[16], kn[16];
    __shared__ int rank[16];
    const int tid = threadIdx.x;
    if (tid < 16) {
        const float w1 = Wd1[tid], b1 = bd1[tid];
        w1s[tid] = w1; b1s[tid] = b1;
        kn[tid] = (w1 != 0.0f) ? (-b1 / w1) : INFINITY;
    }
    __syncthreads();
    if (tid < 16) {
        int rk = 0;
        for (int u = 0; u < 16; ++u) {
            const float ku = kn[u], km = kn[tid];
            if (ku < km || (ku == km && u < tid)) ++rk;
        }
        rank[tid] = rk;
    }
    __syncthreads();
    if (tid < 17 * 12) {
        const int s = tid / 12, h = tid % 12;
        float a = 0.0f, be = bd2[h];
        for (int u = 0; u < 16; ++u) {
            const float w1 = w1s[u], b1 = b1s[u];
            bool act;
            if (w1 > 0.0f)      act = (rank[u] < s);
            else if (w1 < 0.0f) act = (rank[u] >= s);
            else                act = (b1 > 0.0f);
            if (act) {
                const float w2 = Wd2[u * 12 + h];
                a  += w2 * w1;
                be += w2 * b1;
            }
        }
        abPack[tid * 2 + 0] = a;
        abPack[tid * 2 + 1] = be;
    }
    for (int b = tid; b < 2048; b += 256) {
        const float rep = (b + 0.5f) * (1.41422f / 2048.0f);
        int cnt = 0;
        for (int t = 0; t < 16; ++t) cnt += (rep > kn[t]) ? 1 : 0;
        lut[b] = (unsigned char)cnt;
    }
}

// ---------------------------------------------------------------------------
// split_x: x fp32 -> xhi/xlo bf16 row-major
// ---------------------------------------------------------------------------
__global__ __launch_bounds__(256) void split_x_kernel(
    const float* __restrict__ x, unsigned short* __restrict__ xhi,
    unsigned short* __restrict__ xlo)
{
    const size_t t = (size_t)blockIdx.x * 256 + threadIdx.x;
    float vv[8];
    const fx4 a = *(const fx4*)&x[t * 8];
    const fx4 b = *(const fx4*)&x[t * 8 + 4];
    vv[0]=a[0]; vv[1]=a[1]; vv[2]=a[2]; vv[3]=a[3];
    vv[4]=b[0]; vv[5]=b[1]; vv[6]=b[2]; vv[7]=b[3];
    u32x4 hi, lo; split8(vv, hi, lo);
    *(u32x4*)&xhi[t * 8] = hi;
    *(u32x4*)&xlo[t * 8] = lo;
}

// ---------------------------------------------------------------------------
// gemm_mfma (unchanged r10): OMODE 0 q/k bf16 hi/lo heads; 1 vT f16 hi/lo;
// 2 fp32 row-major.
// ---------------------------------------------------------------------------
struct SmemG { u32x4 ah[512]; u32x4 al[512]; u32x4 bh[512]; u32x4 bl[512]; };
struct SmemT { float scr[64 * 68]; };
union SmemU { SmemG g; SmemT t; };

template<int OMODE>
__global__ __launch_bounds__(256) void gemm_mfma_kernel(
    const unsigned short* __restrict__ Ahi, const unsigned short* __restrict__ Alo,
    const unsigned short* __restrict__ Bhi, const unsigned short* __restrict__ Blo,
    const float* __restrict__ bias,
    float* __restrict__ outF,
    unsigned short* __restrict__ Ohi, unsigned short* __restrict__ Olo)
{
    __shared__ SmemU sm;
    const int tid = threadIdx.x;
    const int w = tid >> 6, L = tid & 63;
    const int Lr = L & 15, Lg = L >> 4;
    const int m0 = blockIdx.y * 64, n0 = blockIdx.x * 64;

    fx4 acc[2][2] = {};

    for (int kk = 0; kk < 768; kk += 64) {
        #pragma unroll
        for (int it = 0; it < 2; ++it) {
            const int slot = tid + it * 256;
            const int s = slot >> 6, l = slot & 63;
            const int row = m0 + ((s >> 1) << 4) + (l & 15);
            const int kb = kk + ((s & 1) << 5) + ((l >> 4) << 3);
            sm.g.ah[slot] = *(const u32x4*)&Ahi[(size_t)row * 768 + kb];
            sm.g.al[slot] = *(const u32x4*)&Alo[(size_t)row * 768 + kb];
            const int col = n0 + ((s >> 1) << 4) + (l & 15);
            sm.g.bh[slot] = *(const u32x4*)&Bhi[(size_t)col * 768 + kb];
            sm.g.bl[slot] = *(const u32x4*)&Blo[(size_t)col * 768 + kb];
        }
        __syncthreads();
        #pragma unroll
        for (int kc = 0; kc < 2; ++kc) {
            Frag ah[2], al[2], bh[2], bl[2];
            #pragma unroll
            for (int mm = 0; mm < 2; ++mm) {
                const int rg = (w >> 1) * 2 + mm;
                ah[mm].u = sm.g.ah[(rg * 2 + kc) * 64 + L];
                al[mm].u = sm.g.al[(rg * 2 + kc) * 64 + L];
            }
            #pragma unroll
            for (int nn = 0; nn < 2; ++nn) {
                const int cg = (w & 1) * 2 + nn;
                bh[nn].u = sm.g.bh[(cg * 2 + kc) * 64 + L];
                bl[nn].u = sm.g.bl[(cg * 2 + kc) * 64 + L];
            }
            #pragma unroll
            for (int mm = 0; mm < 2; ++mm)
                #pragma unroll
                for (int nn = 0; nn < 2; ++nn) {
                    acc[mm][nn] = __builtin_amdgcn_mfma_f32_16x16x32_bf16(ah[mm].s, bh[nn].s, acc[mm][nn], 0, 0, 0);
                    acc[mm][nn] = __builtin_amdgcn_mfma_f32_16x16x32_bf16(ah[mm].s, bl[nn].s, acc[mm][nn], 0, 0, 0);
                    acc[mm][nn] = __builtin_amdgcn_mfma_f32_16x16x32_bf16(al[mm].s, bh[nn].s, acc[mm][nn], 0, 0, 0);
                }
        }
        __syncthreads();
    }

    #pragma unroll
    for (int mm = 0; mm < 2; ++mm) {
        const int rl = (w >> 1) * 32 + mm * 16 + Lg * 4;
        #pragma unroll
        for (int nn = 0; nn < 2; ++nn) {
            const int cl = (w & 1) * 32 + nn * 16 + Lr;
            const float bs = bias[n0 + cl];
            #pragma unroll
            for (int r = 0; r < 4; ++r)
                sm.t.scr[(rl + r) * 68 + cl] = acc[mm][nn][r] + bs;
        }
    }
    __syncthreads();

    if (OMODE == 0) {
        const int h = n0 >> 6;
        #pragma unroll
        for (int it = 0; it < 2; ++it) {
            const int t = tid + it * 256;
            const int r = t >> 3, d0 = (t & 7) << 3;
            float vv[8];
            #pragma unroll
            for (int e = 0; e < 8; ++e) vv[e] = sm.t.scr[r * 68 + d0 + e];
            u32x4 hi, lo; split8(vv, hi, lo);
            const int rg = m0 + r, b = rg >> 10, nloc = rg & 1023;
            const size_t o = (((size_t)(b * Hc + h) * Nc + nloc) << 6) + d0;
            *(u32x4*)&Ohi[o] = hi;
            *(u32x4*)&Olo[o] = lo;
        }
    } else if (OMODE == 1) {
        const int b = m0 >> 10, h = n0 >> 6, nbase = m0 & 1023;
        #pragma unroll
        for (int it = 0; it < 2; ++it) {
            const int t = tid + it * 256;
            const int dd = t >> 3, j0 = (t & 7) << 3;
            float vv[8];
            #pragma unroll
            for (int e = 0; e < 8; ++e) vv[e] = sm.t.scr[(j0 + e) * 68 + dd];
            u32x4 hi, lo; split8h(vv, hi, lo);   // f16 hi/lo for PV
            const size_t o = (size_t)((b * Hc + h) * Dc + dd) * Nc + nbase + j0;
            *(u32x4*)&Ohi[o] = hi;
            *(u32x4*)&Olo[o] = lo;
        }
    } else {
        #pragma unroll
        for (int it = 0; it < 4; ++it) {
            const int lin = tid + it * 256;
            const int r = lin >> 4, c4 = (lin & 15) << 2;
            const fx4 v = *(const fx4*)&sm.t.scr[r * 68 + c4];
            *(fx4*)&outF[(size_t)(m0 + r) * 768 + n0 + c4] = v;
        }
    }
}

// ---------------------------------------------------------------------------
// attn_flash (r11): flash loop with K=16 PV (A-frag direct from sv regs),
// V double-buffered (1 barrier/jt), e_ws written straight from regs,
// and the normalize pass fused into the epilogue (norm kernel deleted).
// ---------------------------------------------------------------------------
struct VBuf { u32x4 vh[512]; u32x4 vl[512]; };          // 16 KB
union FlashSmem { VBuf vbuf[2]; float scr[64 * 68]; };  // 32 KB

__global__ __launch_bounds__(256) void attn_flash_kernel(
    const unsigned short* __restrict__ qhi, const unsigned short* __restrict__ qlo,
    const unsigned short* __restrict__ khi, const unsigned short* __restrict__ klo,
    const unsigned short* __restrict__ vThi, const unsigned short* __restrict__ vTlo,
    const float* __restrict__ coords,
    const float* __restrict__ abPack, const unsigned char* __restrict__ lutg,
    unsigned short* __restrict__ e_ws,
    float* __restrict__ attn,
    unsigned short* __restrict__ Hphi, unsigned short* __restrict__ Hplo)
{
    __shared__ FlashSmem sm;
    __shared__ float mTs[64][17];
    __shared__ float ms[64], ils[64];
    __shared__ unsigned char luts[2048];
    __shared__ fx2 abt[17];

    const int tid = threadIdx.x;
    const int w = tid >> 6, L = tid & 63;
    const int Lr = L & 15, Lg = L >> 4;
    const int bh = blockIdx.y, b = bh / Hc, h = bh % Hc;
    const int i0 = blockIdx.x * 64;
    const int iloc = w * 16 + Lr;
    const int i = i0 + iloc;
    const int Lg4 = Lg * 4;

    if (tid < 17) abt[tid] = ((const fx2*)abPack)[tid * Hc + h];
    for (int t = tid; t < 512; t += 256)
        ((uint32_t*)luts)[t] = ((const uint32_t*)lutg)[t];

    Frag qh[2], ql[2];
    #pragma unroll
    for (int kc = 0; kc < 2; ++kc) {
        const size_t o = ((size_t)bh * Nc + i) * 64 + kc * 32 + Lg * 8;
        qh[kc].u = *(const u32x4*)&qhi[o];
        ql[kc].u = *(const u32x4*)&qlo[o];
    }
    const fx2 ci = *(const fx2*)&coords[((size_t)b * Nc + i) * 2];
    const fx2* cjall = (const fx2*)coords + (size_t)b * Nc;

    // prologue: stage V[0] -> vbuf[0]
    #pragma unroll
    for (int it = 0; it < 2; ++it) {
        const int s = tid + it * 256;
        const int l = s & 63;
        const int dd = ((s >> 7) << 4) + (l & 15);
        const int jo = ((s >> 6) & 1) * 32 + ((l >> 4) << 3);
        const size_t off = ((size_t)bh * Dc + dd) * Nc + jo;
        sm.vbuf[0].vh[s] = *(const u32x4*)&vThi[off];
        sm.vbuf[0].vl[s] = *(const u32x4*)&vTlo[off];
    }
    __syncthreads();

    fx4 oacc[4] = {};
    float m_r = -INFINITY, l_r = 0.f;

    for (int jt = 0; jt < 16; ++jt) {
        const int jbase = jt * 64;
        const int cur = jt & 1;

        // prefetch V[jt+1] -> regs
        u32x4 vsh[2], vsl[2];
        if (jt < 15) {
            #pragma unroll
            for (int it = 0; it < 2; ++it) {
                const int s = tid + it * 256;
                const int l = s & 63;
                const int dd = ((s >> 7) << 4) + (l & 15);
                const int jo = jbase + 64 + ((s >> 6) & 1) * 32 + ((l >> 4) << 3);
                const size_t off = ((size_t)bh * Dc + dd) * Nc + jo;
                vsh[it] = *(const u32x4*)&vThi[off];
                vsl[it] = *(const u32x4*)&vTlo[off];
            }
        }

        // QK^T (swapped: A = K rows j, B = Q cols i)
        fx4 acc[4] = {};
        #pragma unroll
        for (int kc = 0; kc < 2; ++kc) {
            Frag kh[4], kl[4];
            #pragma unroll
            for (int cg = 0; cg < 4; ++cg) {
                const size_t o = ((size_t)bh * Nc + jbase + cg * 16 + Lr) * 64 + kc * 32 + Lg * 8;
                kh[cg].u = *(const u32x4*)&khi[o];
                kl[cg].u = *(const u32x4*)&klo[o];
            }
            #pragma unroll
            for (int cg = 0; cg < 4; ++cg) {
                acc[cg] = __builtin_amdgcn_mfma_f32_16x16x32_bf16(kh[cg].s, qh[kc].s, acc[cg], 0, 0, 0);
                acc[cg] = __builtin_amdgcn_mfma_f32_16x16x32_bf16(kl[cg].s, qh[kc].s, acc[cg], 0, 0, 0);
                acc[cg] = __builtin_amdgcn_mfma_f32_16x16x32_bf16(kh[cg].s, ql[kc].s, acc[cg], 0, 0, 0);
            }
        }

        // spatial PL-MLP + combine (coords direct from L1-resident global)
        float sv[16];
        #pragma unroll
        for (int cg = 0; cg < 4; ++cg) {
            #pragma unroll
            for (int r = 0; r < 4; ++r) {
                const fx2 cj = cjall[jbase + cg * 16 + Lg4 + r];
                const float dx = ci[0] - cj[0], dy = ci[1] - cj[1];
                const float dist = sqrtf(fmaf(dx, dx, fmaf(dy, dy, 1e-6f)));
                int bin = (int)(dist * (2048.0f / 1.41422f));
                bin = (bin > 2047) ? 2047 : bin;
                const fx2 ab = abt[luts[bin]];
                sv[cg * 4 + r] = fmaf(acc[cg][r], 0.125f, fmaf(ab[0], dist, ab[1]));
            }
        }

        // per-row (Lr) tile max + e + tile sum
        float tm = sv[0];
        #pragma unroll
        for (int e = 1; e < 16; ++e) tm = fmaxf(tm, sv[e]);
        tm = fmaxf(tm, __shfl_xor(tm, 16));
        tm = fmaxf(tm, __shfl_xor(tm, 32));

        float ts = 0.f;
        #pragma unroll
        for (int e = 0; e < 16; ++e) { sv[e] = __expf(sv[e] - tm); ts += sv[e]; }
        ts += __shfl_xor(ts, 16);
        ts += __shfl_xor(ts, 32);

        if (Lg == 0) mTs[iloc][jt] = tm;

        // e_ws store straight from regs (f16), layout [bh][jt][kc][i][32j]
        const size_t ebase = ((size_t)(bh * 16 + jt) * 2) * 32768 + (size_t)i * 32;
        #pragma unroll
        for (int cg = 0; cg < 4; ++cg) {
            H4b pk;
            #pragma unroll
            for (int r = 0; r < 4; ++r) pk.h4[r] = (_Float16)sv[cg * 4 + r];
            *(u32x2*)&e_ws[ebase + (size_t)(cg >> 1) * 32768 + (cg & 1) * 16 + Lg4] = pk.d;
        }

        // online rescale (row stats in lane Lr; acc rows = Lg4+r -> shfl)
        const float mnew = fmaxf(m_r, tm);
        const float facc = __expf(m_r - mnew);
        const float ftile = __expf(tm - mnew);
        l_r = l_r * facc + ts * ftile;
        m_r = mnew;
        #pragma unroll
        for (int r = 0; r < 4; ++r) {
            const float fr = __shfl(facc, Lg4 + r);
            #pragma unroll
            for (int dg = 0; dg < 4; ++dg) oacc[dg][r] *= fr;
        }

        __syncthreads();   // all waves done reading vbuf[cur^1] (jt-1's PV)
        if (jt < 15) {
            #pragma unroll
            for (int it = 0; it < 2; ++it) {
                const int s = tid + it * 256;
                sm.vbuf[cur ^ 1].vh[s] = vsh[it];
                sm.vbuf[cur ^ 1].vl[s] = vsl[it];
            }
        }

        // PV: K=16 f16 MFMA, A-frag = sv*ftile directly (no LDS permute)
        const char* vhB = (const char*)sm.vbuf[cur].vh;
        const char* vlB = (const char*)sm.vbuf[cur].vl;
        #pragma unroll
        for (int cg = 0; cg < 4; ++cg) {
            H4b a4;
            #pragma unroll
            for (int r = 0; r < 4; ++r) a4.h4[r] = (_Float16)(sv[cg * 4 + r] * ftile);
            const int sub = (cg & 1) * 2 + (Lg >> 1);
            const int kcq = cg >> 1;
            const int low = (Lg & 1) * 8;
            #pragma unroll
            for (int dg = 0; dg < 4; ++dg) {
                const int byteoff = ((dg * 2 + kcq) * 64 + sub * 16 + Lr) * 16 + low;
                H4b bh4, bl4;
                bh4.d = *(const u32x2*)(vhB + byteoff);
                bl4.d = *(const u32x2*)(vlB + byteoff);
                oacc[dg] = __builtin_amdgcn_mfma_f32_16x16x16f16(a4.h4, bh4.h4, oacc[dg], 0, 0, 0);
                oacc[dg] = __builtin_amdgcn_mfma_f32_16x16x16f16(a4.h4, bl4.h4, oacc[dg], 0, 0, 0);
            }
        }
    }

    const float il = 1.0f / l_r;
    if (Lg == 0) { ms[iloc] = m_r; ils[iloc] = il; }
    float il4[4];
    #pragma unroll
    for (int r = 0; r < 4; ++r) il4[r] = __shfl(il, Lg4 + r);

    __syncthreads();   // ms/ils/mTs visible; e_ws drained; vbuf free

    // heads epilogue via scr (aliases vbuf)
    #pragma unroll
    for (int dg = 0; dg < 4; ++dg)
        #pragma unroll
        for (int r = 0; r < 4; ++r)
            sm.scr[(w * 16 + Lg4 + r) * 68 + dg * 16 + Lr] = oacc[dg][r] * il4[r];
    __syncthreads();

    #pragma unroll
    for (int it = 0; it < 2; ++it) {
        const int lin = tid + it * 256;
        const int row = lin >> 3, d0 = (lin & 7) << 3;
        float vv[8];
        #pragma unroll
        for (int e = 0; e < 8; ++e) vv[e] = sm.scr[row * 68 + d0 + e];
        u32x4 hi, lo; split8(vv, hi, lo);
        const size_t o = ((size_t)b * Nc + i0 + row) * Cc + h * Dc + d0;
        *(u32x4*)&Hphi[o] = hi;
        *(u32x4*)&Hplo[o] = lo;
    }

    // fused normalize: attn[row][j] = e * exp(m_t - m_row) * il  (L2-warm e)
    const int irow = tid >> 2;
    const int jj = (tid & 3) << 3;
    const float mrow = ms[irow], ilr = ils[irow];
    const size_t gi = (size_t)(i0 + irow);
    float* arow = attn + ((size_t)bh * Nc + gi) * Nc;
    const unsigned short* ebase2 = e_ws + (size_t)(bh * 16) * 2 * 32768 + gi * 32 + jj;
    for (int jt2 = 0; jt2 < 16; ++jt2) {
        const float f = __expf(mTs[irow][jt2] - mrow) * ilr;
        #pragma unroll
        for (int kc = 0; kc < 2; ++kc) {
            Frag ev;
            ev.u = *(const u32x4*)(ebase2 + ((size_t)jt2 * 2 + kc) * 32768);
            fx4 o0, o1;
            o0[0] = (float)ev.f16[0] * f; o0[1] = (float)ev.f16[1] * f;
            o0[2] = (float)ev.f16[2] * f; o0[3] = (float)ev.f16[3] * f;
            o1[0] = (float)ev.f16[4] * f; o1[1] = (float)ev.f16[5] * f;
            o1[2] = (float)ev.f16[6] * f; o1[3] = (float)ev.f16[7] * f;
            float* ap = &arow[jt2 * 64 + kc * 32 + jj];
            *(fx4*)ap = o0;
            *(fx4*)(ap + 4) = o1;
        }
    }
}

// ---------------------------------------------------------------------------
extern "C" void kernel_launch(void* const* d_in, const int* in_sizes, int n_in,
                              void* d_out, int out_size, void* d_ws, size_t ws_size,
                              hipStream_t stream)
{
    (void)in_sizes; (void)n_in; (void)out_size; (void)ws_size;

    const float* x      = (const float*)d_in[0];
    const float* coords = (const float*)d_in[1];
    const float* Wq = (const float*)d_in[2];  const float* bq = (const float*)d_in[3];
    const float* Wk = (const float*)d_in[4];  const float* bk = (const float*)d_in[5];
    const float* Wv = (const float*)d_in[6];  const float* bv = (const float*)d_in[7];
    const float* Wo = (const float*)d_in[8];  const float* bo = (const float*)d_in[9];
    const float* Wd1 = (const float*)d_in[10]; const float* bd1 = (const float*)d_in[11];
    const float* Wd2 = (const float*)d_in[12]; const float* bd2 = (const float*)d_in[13];

    float* out_main = (float*)d_out;            // [B,N,C]
    float* attn     = out_main + QKV_ELEMS;     // [B,H,N,N]

    uint8_t* wsb = (uint8_t*)d_ws;
    const size_t SZ_BF = (size_t)BHc * Nc * Dc * 2;          // 6,291,456 B
    const size_t SZ_W4 = (size_t)4 * 768 * 768 * 2;          // 4,718,592 B
    unsigned short* qhi  = (unsigned short*)(wsb + 0 * SZ_BF);
    unsigned short* qlo  = (unsigned short*)(wsb + 1 * SZ_BF);
    unsigned short* khi  = (unsigned short*)(wsb + 2 * SZ_BF);
    unsigned short* klo  = (unsigned short*)(wsb + 3 * SZ_BF);
    unsigned short* vThi = (unsigned short*)(wsb + 4 * SZ_BF);
    unsigned short* vTlo = (unsigned short*)(wsb + 5 * SZ_BF);
    unsigned short* xhi  = (unsigned short*)(wsb + 6 * SZ_BF); // reused as Hphi
    unsigned short* xlo  = (unsigned short*)(wsb + 7 * SZ_BF); // reused as Hplo
    unsigned short* Thi  = (unsigned short*)(wsb + 8 * SZ_BF);
    unsigned short* Tlo  = (unsigned short*)(wsb + 8 * SZ_BF + SZ_W4);
    uint8_t* base8 = wsb + 8 * SZ_BF + 2 * SZ_W4;
    float* abPack = (float*)base8;                            // 408 floats
    unsigned char* lut = (unsigned char*)(base8 + 4096);      // 2048 B
    unsigned short* e_ws = (unsigned short*)(base8 + 8192);   // f16 e, 100.7 MB

    prep_w_kernel<<<dim3(12, 12, 4), 256, 0, stream>>>(Wq, Wk, Wv, Wo, Thi, Tlo);
    prep_tables_kernel<<<1, 256, 0, stream>>>(Wd1, bd1, Wd2, bd2, abPack, lut);
    split_x_kernel<<<dim3(1536), 256, 0, stream>>>(x, xhi, xlo);

    dim3 gGemm(12, 64);
    gemm_mfma_kernel<0><<<gGemm, 256, 0, stream>>>(
        xhi, xlo, Thi + (size_t)0 * 768 * 768, Tlo + (size_t)0 * 768 * 768,
        bq, nullptr, qhi, qlo);
    gemm_mfma_kernel<0><<<gGemm, 256, 0, stream>>>(
        xhi, xlo, Thi + (size_t)1 * 768 * 768, Tlo + (size_t)1 * 768 * 768,
        bk, nullptr, khi, klo);
    gemm_mfma_kernel<1><<<gGemm, 256, 0, stream>>>(
        xhi, xlo, Thi + (size_t)2 * 768 * 768, Tlo + (size_t)2 * 768 * 768,
        bv, nullptr, vThi, vTlo);

    attn_flash_kernel<<<dim3(16, 48), 256, 0, stream>>>(
        qhi, qlo, khi, klo, vThi, vTlo, coords, abPack, lut,
        e_ws, attn, xhi, xlo);

    gemm_mfma_kernel<2><<<gGemm, 256, 0, stream>>>(
        xhi, xlo, Thi + (size_t)3 * 768 * 768, Tlo + (size_t)3 * 768 * 768,
        bo, out_main, nullptr, nullptr);
}